// Round 21
// baseline (283.985 us; speedup 1.0000x reference)
//
#include <hip/hip_runtime.h>
#include <hip/hip_bf16.h>
#include <cstdint>
#include <cstddef>

// Problem constants
#define S_DIM 2048
#define H_DIM 2048
#define NHEAD 16
#define HD_DIM 128
#define O3    6144   // 3*H
#define BS    4096   // B*S
#define NBH   32     // B*NHEAD

typedef short  s16x4  __attribute__((ext_vector_type(4)));
typedef short  s16x8  __attribute__((ext_vector_type(8)));
typedef __bf16 bf16x8 __attribute__((ext_vector_type(8)));
typedef float  f32x4  __attribute__((ext_vector_type(4)));

__device__ __forceinline__ unsigned short f2bf(float f) {
  unsigned int b = __float_as_uint(f);
  b += 0x7FFFu + ((b >> 16) & 1u);          // round-to-nearest-even
  return (unsigned short)(b >> 16);
}
__device__ __forceinline__ float bf2f(unsigned short u) {
  return __uint_as_float(((unsigned int)u) << 16);
}
__device__ __forceinline__ bf16x8 load8(const unsigned short* p) {
  s16x8 r = *(const s16x8*)p;
  return __builtin_bit_cast(bf16x8, r);
}
__device__ __forceinline__ f32x4 mfma_bf16(bf16x8 a, bf16x8 b, f32x4 c) {
  return __builtin_amdgcn_mfma_f32_16x16x32_bf16(a, b, c, 0, 0, 0);
}
__device__ __forceinline__ void gload_lds16(const void* g, void* l) {
  __builtin_amdgcn_global_load_lds(
      (__attribute__((address_space(1))) unsigned int*)g,
      (__attribute__((address_space(3))) unsigned int*)l, 16, 0, 0);
}

// -------------------------------------------------- fused prep (one launch)
__global__ void prep_kernel(const float* __restrict__ hid,
                            const float* __restrict__ wqkv,
                            const float* __restrict__ wo,
                            unsigned short* __restrict__ hid_b,
                            unsigned short* __restrict__ wqkv_b,
                            unsigned short* __restrict__ wo_b,
                            float* __restrict__ cosT,
                            float* __restrict__ sinT) {
  const int nA = 2097152, nB = 3145728, nC = 1048576, nD = 131072;
  const int total = nA + nB + nC + nD;
  int stride = gridDim.x * blockDim.x;
  for (int i = blockIdx.x * blockDim.x + threadIdx.x; i < total; i += stride) {
    if (i < nA + nB + nC) {
      const float* src; unsigned short* dst; int j;
      if (i < nA)            { src = hid;  dst = hid_b;  j = i; }
      else if (i < nA + nB)  { src = wqkv; dst = wqkv_b; j = i - nA; }
      else                   { src = wo;   dst = wo_b;   j = i - nA - nB; }
      float4 v = ((const float4*)src)[j];
      ushort4 o;
      o.x = f2bf(v.x); o.y = f2bf(v.y); o.z = f2bf(v.z); o.w = f2bf(v.w);
      ((ushort4*)dst)[j] = o;
    } else {
      int idx = i - nA - nB - nC;          // 0..131071 = s*64 + d
      int s = idx >> 6, d = idx & 63;
      float inv = expf(-((float)d / 64.0f) * 9.210340371976184f);
      float ang = (float)s * inv;
      float sn, cs;
      sincosf(ang, &sn, &cs);
      cosT[idx] = cs;
      sinT[idx] = sn;
    }
  }
}

// --------------------------------- 4-phase counted 256x256 GEMM (B^T), bf16
// C[M][N] = A[M][K] * Bw[N][K]^T. BM=BN=256, BK=64; 512 threads = 8 waves
// (2M x 4N), per-wave C = 128x64 (acc[8][4]).
// K-tile split into two K-HALVES (32 each), stored as contiguous LDS
// half-tiles [buf][half][256r][32k] (A+B = 128KB, 2 buffers).
// Phases per tile: (kk0,g0),(kk0,g1),(kk1,g0),(kk1,g1); 16 MFMA/wave/phase;
// A-frags of a kk read once, reused across both g-phases.
// Staging: 1 half-tile per phase, ONE TILE AHEAD:
//   t.P0: A-K0(t+1)  t.P1: B-K0(t+1)  t.P2: A-K1(t+1)  t.P3: B-K1(t+1)
// Waits: vmcnt(4) at ends of P1 and P3 only (each awaited load has >=2
// phases ~1400cy cover > 900cy HBM; queue never drains below 4):
//   P1-end: outstanding = K0(t+1) A,B (4 loads) -> K1(t) landed for P2.
//   P3-end: outstanding = K1(t+1) A,B (4 loads) -> K0(t+1) landed for t+1.P0.
// LDS swizzle: chunk kc ^= (r>>1)&3 (involution; bank-walk = 2-way max);
// DMA source pre-swizzled with the same involution (G21).
__global__ __launch_bounds__(512, 1)
void gemm256p_kernel(const unsigned short* __restrict__ A,
                     const unsigned short* __restrict__ Bw,
                     unsigned short* __restrict__ C, int M, int N, int K) {
  __shared__ __align__(16) unsigned short lA[2][2][8192];  // 64KB
  __shared__ __align__(16) unsigned short lB[2][2][8192];  // 64KB
  const int tid  = threadIdx.x;
  const int wave = tid >> 6, lane = tid & 63;
  const int wm = wave >> 2, wn = wave & 3;       // 2M x 4N wave grid
  const int lg = lane >> 4, ll = lane & 15;

  // chunked XCD swizzle (nwg = 384, % 8 == 0)
  const int nbx = gridDim.x;
  const int nwg = gridDim.x * gridDim.y;
  const int id  = blockIdx.y * nbx + blockIdx.x;
  const int swz = (id & 7) * (nwg >> 3) + (id >> 3);
  const int m0 = (swz / nbx) * 256, n0 = (swz % nbx) * 256;

  f32x4 acc[8][4];
#pragma unroll
  for (int i = 0; i < 8; ++i)
#pragma unroll
    for (int j = 0; j < 4; ++j) acc[i][j] = (f32x4){0.f, 0.f, 0.f, 0.f};

  // staging: half-tile = 1024 chunks (256r x 4kc), 2 chunks/thread.
  // dest linear cb; source chunk cs = cb ^ ((cb>>3)&3) (involution on kc).
  const unsigned short* aSrc[2];
  const unsigned short* bSrc[2];
  int dOff[2];
#pragma unroll
  for (int i = 0; i < 2; ++i) {
    int cb = i * 512 + tid;
    int cs = cb ^ ((cb >> 3) & 3);
    int row = cs >> 2, kc = cs & 3;
    aSrc[i] = A + (size_t)(m0 + row) * K + kc * 8;
    bSrc[i] = Bw + (size_t)(n0 + row) * K + kc * 8;
    dOff[i] = cb * 8;
  }
  auto STG_A = [&](int buf, int kkh, int kt) {
#pragma unroll
    for (int i = 0; i < 2; ++i)
      gload_lds16(aSrc[i] + kt + kkh * 32, &lA[buf][kkh][dOff[i]]);
  };
  auto STG_B = [&](int buf, int kkh, int kt) {
#pragma unroll
    for (int i = 0; i < 2; ++i)
      gload_lds16(bSrc[i] + kt + kkh * 32, &lB[buf][kkh][dOff[i]]);
  };

  // fragment read: row r, chunk kc' = lg ^ ((r>>1)&3), elem = r*32 + kc'*8
  const int NT = K >> 6;   // 32
  // prologue: all 4 halves of tile 0; vmcnt(4) -> K0(0) landed, K1(0) afloat
  STG_A(0, 0, 0); STG_B(0, 0, 0); STG_A(0, 1, 0); STG_B(0, 1, 0);
  asm volatile("s_waitcnt vmcnt(4)" ::: "memory");
  asm volatile("s_barrier" ::: "memory");

  for (int t = 0; t < NT; ++t) {
    const int buf = t & 1, nbuf = buf ^ 1;
    const int ktn = (t + 1) << 6;
    const bool st = (t + 1 < NT);
    bf16x8 af[8], bf[2];

#pragma unroll
    for (int kk = 0; kk < 2; ++kk) {
      const unsigned short* la = &lA[buf][kk][0];
      const unsigned short* lb = &lB[buf][kk][0];
      // ---- phase (kk, g=0): read A-frags (reused) + B fn 0,1; stage; MFMA
#pragma unroll
      for (int fm = 0; fm < 8; ++fm) {
        int r = wm * 128 + fm * 16 + ll;
        af[fm] = load8(la + r * 32 + (lg ^ ((r >> 1) & 3)) * 8);
      }
#pragma unroll
      for (int gq = 0; gq < 2; ++gq) {
        int r = wn * 64 + gq * 16 + ll;
        bf[gq] = load8(lb + r * 32 + (lg ^ ((r >> 1) & 3)) * 8);
      }
      if (st) { if (kk == 0) STG_A(nbuf, 0, ktn); else STG_A(nbuf, 1, ktn); }
      asm volatile("s_barrier" ::: "memory");
      asm volatile("s_waitcnt lgkmcnt(0)" ::: "memory");
      __builtin_amdgcn_sched_barrier(0);
      __builtin_amdgcn_s_setprio(1);
#pragma unroll
      for (int fm = 0; fm < 8; ++fm)
#pragma unroll
        for (int gq = 0; gq < 2; ++gq)
          acc[fm][gq] = mfma_bf16(af[fm], bf[gq], acc[fm][gq]);
      __builtin_amdgcn_s_setprio(0);
      __builtin_amdgcn_sched_barrier(0);
      asm volatile("s_barrier" ::: "memory");

      // ---- phase (kk, g=1): read B fn 2,3; stage; vmcnt(4); MFMA
#pragma unroll
      for (int gq = 0; gq < 2; ++gq) {
        int r = wn * 64 + (2 + gq) * 16 + ll;
        bf[gq] = load8(lb + r * 32 + (lg ^ ((r >> 1) & 3)) * 8);
      }
      if (st) { if (kk == 0) STG_B(nbuf, 0, ktn); else STG_B(nbuf, 1, ktn); }
      asm volatile("s_barrier" ::: "memory");
      asm volatile("s_waitcnt lgkmcnt(0)" ::: "memory");
      __builtin_amdgcn_sched_barrier(0);
      __builtin_amdgcn_s_setprio(1);
#pragma unroll
      for (int fm = 0; fm < 8; ++fm)
#pragma unroll
        for (int gq = 0; gq < 2; ++gq)
          acc[fm][2 + gq] = mfma_bf16(af[fm], bf[gq], acc[fm][2 + gq]);
      __builtin_amdgcn_s_setprio(0);
      __builtin_amdgcn_sched_barrier(0);
      // counted wait: allow only the 4 newest loads outstanding.
      // kk=0 (P1-end): K1(t) landed for the next two phases.
      // kk=1 (P3-end): K0(t+1) landed for t+1's first phase.
      asm volatile("s_waitcnt vmcnt(4)" ::: "memory");
      asm volatile("s_barrier" ::: "memory");
    }
  }

  // epilogue: C/D frag layout col = lane&15, row = (lane>>4)*4 + j
#pragma unroll
  for (int fm = 0; fm < 8; ++fm)
#pragma unroll
    for (int fn = 0; fn < 4; ++fn)
#pragma unroll
      for (int j = 0; j < 4; ++j) {
        int r   = m0 + wm * 128 + fm * 16 + lg * 4 + j;
        int col = n0 + wn * 64 + fn * 16 + ll;
        C[(size_t)r * N + col] = f2bf(acc[fm][fn][j]);
      }
}

// ------------------------------------------------- triple-buffered GEMM (B^T)
// Kept for the output projection (256 blocks = exactly 1 round there).
template <bool OUT_BF16, bool QKV_MAP>
__global__ __launch_bounds__(512, 1)
void gemm3b_kernel(const unsigned short* __restrict__ A,
                   const unsigned short* __restrict__ Bw,
                   void* __restrict__ C, int M, int N, int K) {
  __shared__ __align__(16) unsigned short lA[3][128 * 64];   // 3 x 16KB
  __shared__ __align__(16) unsigned short lB[3][256 * 64];   // 3 x 32KB
  const int tid  = threadIdx.x;
  const int wave = tid >> 6, lane = tid & 63;
  const int wm = wave >> 2, wn = wave & 3;       // 2M x 4N wave grid
  const int lg = lane >> 4, ll = lane & 15;

  const int nbx = gridDim.x;
  const int id  = blockIdx.y * nbx + blockIdx.x;
  int m_tile, n_tile;
  if (QKV_MAP) {
    const int k = id & 7, q = id >> 3;
    const int ng = q >> 5, r = q & 31;
    m_tile = (k >> 1) * 8 + (r & 7);
    n_tile = (k & 1) * 12 + ng * 4 + (r >> 3);
  } else {
    const int nwg = gridDim.x * gridDim.y;
    const int swz = (id & 7) * (nwg >> 3) + (id >> 3);
    m_tile = swz / nbx;
    n_tile = swz % nbx;
  }
  const int m0 = m_tile * 128, n0 = n_tile * 256;

  f32x4 acc[4][4];
#pragma unroll
  for (int i = 0; i < 4; ++i)
#pragma unroll
    for (int j = 0; j < 4; ++j) acc[i][j] = (f32x4){0.f, 0.f, 0.f, 0.f};

  const unsigned short* aP[2];
  const unsigned short* bP[4];
  int aD[2], bD[4];
#pragma unroll
  for (int i = 0; i < 2; ++i) {
    int cb = (i * 8 + wave) * 64 + lane;
    int cs = cb ^ ((cb >> 3) & 7);
    aP[i] = A + (size_t)(m0 + (cs >> 3)) * K + (cs & 7) * 8;
    aD[i] = cb * 8;
  }
#pragma unroll
  for (int i = 0; i < 4; ++i) {
    int cb = (i * 8 + wave) * 64 + lane;
    int cs = cb ^ ((cb >> 3) & 7);
    bP[i] = Bw + (size_t)(n0 + (cs >> 3)) * K + (cs & 7) * 8;
    bD[i] = cb * 8;
  }

  auto STAGE = [&](int buf, int t) {
    const int kt = t << 6;
#pragma unroll
    for (int i = 0; i < 2; ++i) gload_lds16(aP[i] + kt, &lA[buf][aD[i]]);
#pragma unroll
    for (int i = 0; i < 4; ++i) gload_lds16(bP[i] + kt, &lB[buf][bD[i]]);
  };

  const int NT = K >> 6;
  STAGE(0, 0);
  if (NT > 1) {
    STAGE(1, 1);
    asm volatile("s_waitcnt vmcnt(6)" ::: "memory");
  } else {
    asm volatile("s_waitcnt vmcnt(0)" ::: "memory");
  }
  asm volatile("s_barrier" ::: "memory");

  for (int t = 0; t < NT; ++t) {
    const int cur = t % 3;
    const char* lAc = (const char*)&lA[cur][0];
    const char* lBc = (const char*)&lB[cur][0];

    bf16x8 af[4][2], bfr[2][2][2];
#pragma unroll
    for (int fq = 0; fq < 4; ++fq) {
      int r = wm * 64 + fq * 16 + ll;
#pragma unroll
      for (int kk = 0; kk < 2; ++kk) {
        int a = (r * 128 + kk * 64 + lg * 16) ^ ((r & 7) << 4);
        af[fq][kk] = load8((const unsigned short*)(lAc + a));
      }
    }
#pragma unroll
    for (int nh = 0; nh < 2; ++nh)
#pragma unroll
      for (int fq = 0; fq < 2; ++fq) {
        int r = wn * 64 + nh * 32 + fq * 16 + ll;
#pragma unroll
        for (int kk = 0; kk < 2; ++kk) {
          int a = (r * 128 + kk * 64 + lg * 16) ^ ((r & 7) << 4);
          bfr[nh][fq][kk] = load8((const unsigned short*)(lBc + a));
        }
      }

    if (t + 2 < NT) STAGE((t + 2) % 3, t + 2);

    __builtin_amdgcn_s_setprio(1);
#pragma unroll
    for (int nh = 0; nh < 2; ++nh)
#pragma unroll
      for (int fq = 0; fq < 4; ++fq)
#pragma unroll
        for (int gq = 0; gq < 2; ++gq)
#pragma unroll
          for (int kk = 0; kk < 2; ++kk)
            acc[fq][nh * 2 + gq] =
                mfma_bf16(af[fq][kk], bfr[nh][gq][kk], acc[fq][nh * 2 + gq]);
    __builtin_amdgcn_s_setprio(0);

    if (t + 2 < NT)
      asm volatile("s_waitcnt vmcnt(6)" ::: "memory");
    else if (t + 1 < NT)
      asm volatile("s_waitcnt vmcnt(0)" ::: "memory");
    asm volatile("s_barrier" ::: "memory");
  }

#pragma unroll
  for (int fm = 0; fm < 4; ++fm)
#pragma unroll
    for (int fn = 0; fn < 4; ++fn)
#pragma unroll
      for (int j = 0; j < 4; ++j) {
        int r   = m0 + wm * 64 + fm * 16 + lg * 4 + j;
        int col = n0 + wn * 64 + fn * 16 + ll;
        if (OUT_BF16)
          ((unsigned short*)C)[(size_t)r * N + col] = f2bf(acc[fm][fn][j]);
        else
          ((float*)C)[(size_t)r * N + col] = acc[fm][fn][j];
      }
}

// ---------------------------------------------------------------- RoPE q,k
__global__ void rope_qk_kernel(const unsigned short* __restrict__ mixed,
                               const float* __restrict__ cosT,
                               const float* __restrict__ sinT,
                               unsigned short* __restrict__ qr,
                               unsigned short* __restrict__ kr) {
  int m = blockIdx.x;              // 0..BS-1
  int s = m & (S_DIM - 1);
  int b = m >> 11;
  const unsigned short* row = mixed + (size_t)m * O3;
  int t = threadIdx.x;
  int h = t >> 4, dg = (t & 15) << 2;   // d = dg..dg+3
  int base = h * 384;
  s16x4 q0 = *(const s16x4*)(row + base + dg);
  s16x4 q1 = *(const s16x4*)(row + base + 64 + dg);
  s16x4 k0 = *(const s16x4*)(row + base + 128 + dg);
  s16x4 k1 = *(const s16x4*)(row + base + 192 + dg);
  float4 c4 = *(const float4*)(cosT + (s << 6) + dg);
  float4 s4 = *(const float4*)(sinT + (s << 6) + dg);
  size_t ob = ((size_t)(b * NHEAD + h) * S_DIM + s) * HD_DIM;
  s16x4 oq0, oq1, ok0, ok1;
  float cc[4] = {c4.x, c4.y, c4.z, c4.w};
  float ss[4] = {s4.x, s4.y, s4.z, s4.w};
#pragma unroll
  for (int i = 0; i < 4; ++i) {
    float q0f = bf2f((unsigned short)q0[i]), q1f = bf2f((unsigned short)q1[i]);
    float k0f = bf2f((unsigned short)k0[i]), k1f = bf2f((unsigned short)k1[i]);
    oq0[i] = (short)f2bf(q0f * cc[i] - q1f * ss[i]);
    oq1[i] = (short)f2bf(q1f * cc[i] + q0f * ss[i]);
    ok0[i] = (short)f2bf(k0f * cc[i] - k1f * ss[i]);
    ok1[i] = (short)f2bf(k1f * cc[i] + k0f * ss[i]);
  }
  *(s16x4*)(qr + ob + dg)      = oq0;
  *(s16x4*)(qr + ob + 64 + dg) = oq1;
  *(s16x4*)(kr + ob + dg)      = ok0;
  *(s16x4*)(kr + ob + 64 + dg) = ok1;
}

// ---------------------------------------------------------------- V transpose
__global__ __launch_bounds__(256)
void vtrans_kernel(const unsigned short* __restrict__ mixed,
                   unsigned short* __restrict__ vt) {
  __shared__ unsigned short t[64 * 65];
  int st = blockIdx.x, dt = blockIdx.y, bh = blockIdx.z;
  int b = bh >> 4, h = bh & 15;
  int s0 = st * 64, d0 = dt * 64;
  int tid = threadIdx.x;
#pragma unroll
  for (int it = 0; it < 2; ++it) {
    int c = it * 256 + tid;                 // 0..511
    int sl = c >> 3, dc = c & 7;
    const unsigned short* src =
        mixed + (size_t)(b * S_DIM + s0 + sl) * O3 + h * 384 + 256 + d0 + dc * 8;
    s16x8 v = *(const s16x8*)src;
#pragma unroll
    for (int i = 0; i < 8; ++i) t[(dc * 8 + i) * 65 + sl] = (unsigned short)v[i];
  }
  __syncthreads();
#pragma unroll
  for (int it = 0; it < 2; ++it) {
    int c = it * 256 + tid;
    int dl = c >> 3, sc = c & 7;
    s16x8 v;
#pragma unroll
    for (int i = 0; i < 8; ++i) v[i] = (short)t[dl * 65 + sc * 8 + i];
    *(s16x8*)(vt + ((size_t)bh * HD_DIM + d0 + dl) * S_DIM + s0 + sc * 8) = v;
  }
}

// ---------------------------------------------------------------- attention
// 8-wave: grid (p=8, bh=32) = 256 blocks, 512 threads, 128 q-rows/block.
// Pairing {p, 15-p} -> 36 kv64-tiles every block. Mask: last two tiles.
__global__ __launch_bounds__(512, 1)
void attn_kernel(const unsigned short* __restrict__ qr,
                 const unsigned short* __restrict__ kr,
                 const unsigned short* __restrict__ vt,
                 unsigned short* __restrict__ out) {
  __shared__ __align__(16) unsigned short kbuf[2][64 * 128]; // 16KB/buf rows=s
  __shared__ __align__(16) unsigned short vbuf[2][128 * 64]; // 16KB/buf rows=d
  __shared__ __align__(16) unsigned short plds[8][16 * 72];  // per-wave P
  const int p = blockIdx.x, bh = blockIdx.y;
  const int wave = threadIdx.x >> 6, lane = threadIdx.x & 63;
  const int b = bh >> 4, h = bh & 15;
  const int lg = lane >> 4, ll = lane & 15;
  const unsigned short* Qb = qr + (size_t)bh * S_DIM * HD_DIM;
  const unsigned short* Kb = kr + (size_t)bh * S_DIM * HD_DIM;
  const unsigned short* Vb = vt + (size_t)bh * HD_DIM * S_DIM;
  const float kE  = 0.12752792f;   // (1/sqrt(128)) * log2(e)
  const float THR = 11.5416f;      // 8 * log2(e)  (T13 threshold, k-domain)
  unsigned short* pw = &plds[wave][0];

  for (int seg = 0; seg < 2; ++seg) {
    const int qt = seg ? (15 - p) : p;         // 128-row q-tile index
    const int qbase = qt * 128 + wave * 16;
    const int ntb = 2 * qt + 2;                // causal kv64-tile count

    auto STAGE = [&](int buf, int t) {
      const int k0 = t * 64;
#pragma unroll
      for (int i = 0; i < 2; ++i) {
        int cb = (i * 8 + wave) * 64;      // wave-uniform
        int c  = cb + lane;                // K chunk 0..1023 (16/row)
        int cs = c ^ ((c >> 4) & 7);
        gload_lds16(Kb + (size_t)(k0 + (cs >> 4)) * HD_DIM + (cs & 15) * 8,
                    &kbuf[buf][cb * 8]);
      }
#pragma unroll
      for (int i = 0; i < 2; ++i) {
        int cb = (i * 8 + wave) * 64;
        int c  = cb + lane;                // V chunk 0..1023 (8/row)
        int cv = c ^ ((c >> 3) & 7);
        gload_lds16(Vb + (size_t)(cv >> 3) * S_DIM + k0 + (cv & 7) * 8,
                    &vbuf[buf][cb * 8]);
      }
    };

    bf16x8 aq[4];
#pragma unroll
    for (int kk = 0; kk < 4; ++kk)
      aq[kk] = load8(Qb + (size_t)(qbase + ll) * HD_DIM + kk * 32 + lg * 8);

    float mk[4], lsum[4];
    f32x4 o[8];
#pragma unroll
    for (int j = 0; j < 4; ++j) { mk[j] = -1e30f; lsum[j] = 0.f; }
#pragma unroll
    for (int f = 0; f < 8; ++f) o[f] = (f32x4){0.f, 0.f, 0.f, 0.f};

    STAGE(0, 0);
    __syncthreads();   // implicit vmcnt(0) drain

    for (int t = 0; t < ntb; ++t) {
      const int cur = t & 1;
      if (t + 1 < ntb) STAGE(cur ^ 1, t + 1);  // overlap with this tile's work
      const int k0 = t * 64;
      const bool maskt = (t >= ntb - 2);       // block-uniform mask window

      // ---- QK^T: s[kf] covers kv rows k0+kf*16..+16, K from swizzled LDS
      f32x4 s[4];
#pragma unroll
      for (int kf = 0; kf < 4; ++kf) s[kf] = (f32x4){0.f, 0.f, 0.f, 0.f};
      const char* kb = (const char*)&kbuf[cur][0];
      __builtin_amdgcn_s_setprio(1);
#pragma unroll
      for (int kf = 0; kf < 4; ++kf) {
        int r = kf * 16 + ll;
#pragma unroll
        for (int kk = 0; kk < 4; ++kk) {
          int a = (r * 256 + kk * 64 + lg * 16) ^ ((r & 7) << 4);
          s[kf] = mfma_bf16(aq[kk], load8((const unsigned short*)(kb + a)), s[kf]);
        }
      }
      __builtin_amdgcn_s_setprio(0);

      // ---- causal mask (last two tiles only; raw-score domain)
      if (maskt) {
#pragma unroll
        for (int kf = 0; kf < 4; ++kf) {
          int kcol = k0 + kf * 16 + ll;
#pragma unroll
          for (int j = 0; j < 4; ++j) {
            int qrow = qbase + lg * 4 + j;
            if (kcol > qrow) s[kf][j] = -1e31f;
          }
        }
      }

      // ---- defer-max online softmax (T13). mk is running max * kE.
      float pmax[4];
      bool ok = true;
#pragma unroll
      for (int j = 0; j < 4; ++j) {
        pmax[j] = fmaxf(fmaxf(s[0][j], s[1][j]), fmaxf(s[2][j], s[3][j]));
        ok = ok && (pmax[j] * kE - mk[j] <= THR);
      }
      if (!__all(ok)) {                      // rare: ~once per segment
#pragma unroll
        for (int j = 0; j < 4; ++j) {
          float rm = pmax[j] * kE;
#pragma unroll
          for (int off = 1; off < 16; off <<= 1)
            rm = fmaxf(rm, __shfl_xor(rm, off, 64));
          rm = fmaxf(rm, mk[j]);
          float corr = exp2f(mk[j] - rm);
          mk[j] = rm;
          lsum[j] *= corr;
#pragma unroll
          for (int f = 0; f < 8; ++f) o[f][j] *= corr;
        }
      }
      // P = exp2(s*kE - mk)  (bounded by 2^THR = e^8); per-lane l partials.
#pragma unroll
      for (int j = 0; j < 4; ++j) {
        int prow = (lg * 4 + j) * 72;
#pragma unroll
        for (int kf = 0; kf < 4; ++kf) {
          float e = exp2f(fmaf(s[kf][j], kE, -mk[j]));
          lsum[j] += e;
          pw[prow + kf * 16 + ll] = f2bf(e);
        }
      }

      // ---- PV from swizzled V LDS (P round-trip through per-wave LDS)
      bf16x8 pa0 = load8(&pw[ll * 72 + lg * 8]);
      bf16x8 pa1 = load8(&pw[ll * 72 + 32 + lg * 8]);
      const char* vb = (const char*)&vbuf[cur][0];
      __builtin_amdgcn_s_setprio(1);
#pragma unroll
      for (int f = 0; f < 8; ++f) {
        int rv = f * 16 + ll;
        int a0 = (rv * 128 + lg * 16) ^ ((rv & 7) << 4);
        int a1 = (rv * 128 + 64 + lg * 16) ^ ((rv & 7) << 4);
        o[f] = mfma_bf16(pa0, load8((const unsigned short*)(vb + a0)), o[f]);
        o[f] = mfma_bf16(pa1, load8((const unsigned short*)(vb + a1)), o[f]);
      }
      __builtin_amdgcn_s_setprio(0);

      __syncthreads();   // drains vmcnt (next tile staged) + protects buffers
    }

    // ---- epilogue: reduce l partials once, normalize, store
#pragma unroll
    for (int j = 0; j < 4; ++j) {
      float l = lsum[j];
#pragma unroll
      for (int off = 1; off < 16; off <<= 1) l += __shfl_xor(l, off, 64);
      lsum[j] = 1.0f / l;
    }
#pragma unroll
    for (int f = 0; f < 8; ++f)
#pragma unroll
      for (int j = 0; j < 4; ++j) {
        int srow = qbase + lg * 4 + j;
        out[((size_t)(b * S_DIM + srow)) * H_DIM + h * HD_DIM + f * 16 + ll] =
            f2bf(o[f][j] * lsum[j]);
      }
  }
}

// ---------------------------------------------------------------- launch
extern "C" void kernel_launch(void* const* d_in, const int* in_sizes, int n_in,
                              void* d_out, int out_size, void* d_ws, size_t ws_size,
                              hipStream_t stream) {
  (void)in_sizes; (void)n_in; (void)out_size; (void)ws_size;
  const float* hidden = (const float*)d_in[0];
  const float* wqkv   = (const float*)d_in[1];
  const float* wo     = (const float*)d_in[2];
  char* ws = (char*)d_ws;
  unsigned short* hid_b  = (unsigned short*)(ws);               // 16,777,216
  unsigned short* wqkv_b = (unsigned short*)(ws + 16777216);    // 25,165,824
  unsigned short* wo_b   = (unsigned short*)(ws + 41943040);    //  8,388,608
  unsigned short* mixed  = (unsigned short*)(ws + 50331648);    // 50,331,648
  unsigned short* q_r    = (unsigned short*)(ws + 100663296);   // 16,777,216
  unsigned short* k_r    = (unsigned short*)(ws + 117440512);   // 16,777,216
  unsigned short* v_t    = (unsigned short*)(ws + 134217728);   // 16,777,216
  unsigned short* attn   = (unsigned short*)(ws + 150994944);   // 16,777,216
  float* cosT            = (float*)(ws + 167772160);            //    524,288
  float* sinT            = (float*)(ws + 168296448);            //    524,288

  prep_kernel<<<2048, 256, 0, stream>>>(hidden, wqkv, wo, hid_b, wqkv_b, wo_b,
                                        cosT, sinT);

  // QKV projection: 4-phase counted 256^2, grid 24x16 = 384 blocks
  gemm256p_kernel<<<dim3(O3 / 256, BS / 256), 512, 0, stream>>>(
      hid_b, wqkv_b, mixed, BS, O3, H_DIM);

  rope_qk_kernel<<<BS, 256, 0, stream>>>(mixed, cosT, sinT, q_r, k_r);
  vtrans_kernel<<<dim3(32, 2, 32), 256, 0, stream>>>(mixed, v_t);

  // attention: 8-wave blocks, grid 8x32 = 256 blocks = exactly 1/CU
  attn_kernel<<<dim3(8, 32), 512, 0, stream>>>(q_r, k_r, v_t, attn);

  // output projection: grid 8x32 = 256 = exactly 1 round; chunked map
  gemm3b_kernel<false, false><<<dim3(H_DIM / 256, BS / 128), 512, 0, stream>>>(
      attn, wo_b, d_out, BS, H_DIM, H_DIM);
}

// Round 22
// 264.843 us; speedup vs baseline: 1.0723x; 1.0723x over previous
//
#include <hip/hip_runtime.h>
#include <hip/hip_bf16.h>
#include <cstdint>
#include <cstddef>

// Problem constants
#define S_DIM 2048
#define H_DIM 2048
#define NHEAD 16
#define HD_DIM 128
#define O3    6144   // 3*H
#define BS    4096   // B*S
#define NBH   32     // B*NHEAD

typedef short  s16x4  __attribute__((ext_vector_type(4)));
typedef short  s16x8  __attribute__((ext_vector_type(8)));
typedef __bf16 bf16x8 __attribute__((ext_vector_type(8)));
typedef float  f32x4  __attribute__((ext_vector_type(4)));

__device__ __forceinline__ unsigned short f2bf(float f) {
  unsigned int b = __float_as_uint(f);
  b += 0x7FFFu + ((b >> 16) & 1u);          // round-to-nearest-even
  return (unsigned short)(b >> 16);
}
__device__ __forceinline__ float bf2f(unsigned short u) {
  return __uint_as_float(((unsigned int)u) << 16);
}
__device__ __forceinline__ bf16x8 load8(const unsigned short* p) {
  s16x8 r = *(const s16x8*)p;
  return __builtin_bit_cast(bf16x8, r);
}
__device__ __forceinline__ f32x4 mfma_bf16(bf16x8 a, bf16x8 b, f32x4 c) {
  return __builtin_amdgcn_mfma_f32_16x16x32_bf16(a, b, c, 0, 0, 0);
}
__device__ __forceinline__ void gload_lds16(const void* g, void* l) {
  __builtin_amdgcn_global_load_lds(
      (__attribute__((address_space(1))) unsigned int*)g,
      (__attribute__((address_space(3))) unsigned int*)l, 16, 0, 0);
}

// -------------------------------------------------- fused prep (one launch)
__global__ void prep_kernel(const float* __restrict__ hid,
                            const float* __restrict__ wqkv,
                            const float* __restrict__ wo,
                            unsigned short* __restrict__ hid_b,
                            unsigned short* __restrict__ wqkv_b,
                            unsigned short* __restrict__ wo_b,
                            float* __restrict__ cosT,
                            float* __restrict__ sinT) {
  const int nA = 2097152, nB = 3145728, nC = 1048576, nD = 131072;
  const int total = nA + nB + nC + nD;
  int stride = gridDim.x * blockDim.x;
  for (int i = blockIdx.x * blockDim.x + threadIdx.x; i < total; i += stride) {
    if (i < nA + nB + nC) {
      const float* src; unsigned short* dst; int j;
      if (i < nA)            { src = hid;  dst = hid_b;  j = i; }
      else if (i < nA + nB)  { src = wqkv; dst = wqkv_b; j = i - nA; }
      else                   { src = wo;   dst = wo_b;   j = i - nA - nB; }
      float4 v = ((const float4*)src)[j];
      ushort4 o;
      o.x = f2bf(v.x); o.y = f2bf(v.y); o.z = f2bf(v.z); o.w = f2bf(v.w);
      ((ushort4*)dst)[j] = o;
    } else {
      int idx = i - nA - nB - nC;          // 0..131071 = s*64 + d
      int s = idx >> 6, d = idx & 63;
      float inv = expf(-((float)d / 64.0f) * 9.210340371976184f);
      float ang = (float)s * inv;
      float sn, cs;
      sincosf(ang, &sn, &cs);
      cosT[idx] = cs;
      sinT[idx] = sn;
    }
  }
}

// ------------------------------------------------- triple-buffered GEMM (B^T)
// PROVEN BEST (r10/r11/r18/r20: QKV 115.7-116.5us, MfmaUtil ~38%).
// BM=128, BN=256, BK=64; 512 threads = 8 waves (2M x 4N), 64x64 C per wave.
// 3 LDS buffers: compute tile t from buf[t%3], tile t+1 landed, t+2 staging
// -> boundary wait vmcnt(6), never drain-0 in the loop (T4). Free-running
// waves within the tile (no mid-tile barriers) — that wave-level overlap is
// what every phase-split attempt failed to beat (151/145/133 vs 116 ledger).
template <bool OUT_BF16, bool QKV_MAP>
__global__ __launch_bounds__(512, 1)
void gemm3b_kernel(const unsigned short* __restrict__ A,
                   const unsigned short* __restrict__ Bw,
                   void* __restrict__ C, int M, int N, int K) {
  __shared__ __align__(16) unsigned short lA[3][128 * 64];   // 3 x 16KB
  __shared__ __align__(16) unsigned short lB[3][256 * 64];   // 3 x 32KB
  const int tid  = threadIdx.x;
  const int wave = tid >> 6, lane = tid & 63;
  const int wm = wave >> 2, wn = wave & 3;       // 2M x 4N wave grid
  const int lg = lane >> 4, ll = lane & 15;

  const int nbx = gridDim.x;
  const int id  = blockIdx.y * nbx + blockIdx.x;
  int m_tile, n_tile;
  if (QKV_MAP) {
    // grid 24(n) x 32(m): XCD k=id&7 -> (mband,nband)=(k>>1,k&1);
    // within: windows of 8m x 4n. Bijective. (r11: FETCH 307->98 MB)
    const int k = id & 7, q = id >> 3;
    const int ng = q >> 5, r = q & 31;
    m_tile = (k >> 1) * 8 + (r & 7);
    n_tile = (k & 1) * 12 + ng * 4 + (r >> 3);
  } else {
    // chunked XCD swizzle (nwg % 8 == 0)
    const int nwg = gridDim.x * gridDim.y;
    const int swz = (id & 7) * (nwg >> 3) + (id >> 3);
    m_tile = swz / nbx;
    n_tile = swz % nbx;
  }
  const int m0 = m_tile * 128, n0 = n_tile * 256;

  f32x4 acc[4][4];
#pragma unroll
  for (int i = 0; i < 4; ++i)
#pragma unroll
    for (int j = 0; j < 4; ++j) acc[i][j] = (f32x4){0.f, 0.f, 0.f, 0.f};

  // hoisted staging addresses; source pre-swizzled with the read involution
  // cs = cb ^ ((cb>>3)&7) (G21).
  const unsigned short* aP[2];
  const unsigned short* bP[4];
  int aD[2], bD[4];
#pragma unroll
  for (int i = 0; i < 2; ++i) {
    int cb = (i * 8 + wave) * 64 + lane;
    int cs = cb ^ ((cb >> 3) & 7);
    aP[i] = A + (size_t)(m0 + (cs >> 3)) * K + (cs & 7) * 8;
    aD[i] = cb * 8;
  }
#pragma unroll
  for (int i = 0; i < 4; ++i) {
    int cb = (i * 8 + wave) * 64 + lane;
    int cs = cb ^ ((cb >> 3) & 7);
    bP[i] = Bw + (size_t)(n0 + (cs >> 3)) * K + (cs & 7) * 8;
    bD[i] = cb * 8;
  }

  auto STAGE = [&](int buf, int t) {
    const int kt = t << 6;
#pragma unroll
    for (int i = 0; i < 2; ++i) gload_lds16(aP[i] + kt, &lA[buf][aD[i]]);
#pragma unroll
    for (int i = 0; i < 4; ++i) gload_lds16(bP[i] + kt, &lB[buf][bD[i]]);
  };

  const int NT = K >> 6;
  STAGE(0, 0);
  if (NT > 1) {
    STAGE(1, 1);
    asm volatile("s_waitcnt vmcnt(6)" ::: "memory");
  } else {
    asm volatile("s_waitcnt vmcnt(0)" ::: "memory");
  }
  asm volatile("s_barrier" ::: "memory");

  for (int t = 0; t < NT; ++t) {
    const int cur = t % 3;
    const char* lAc = (const char*)&lA[cur][0];
    const char* lBc = (const char*)&lB[cur][0];

    bf16x8 af[4][2], bfr[2][2][2];
#pragma unroll
    for (int fq = 0; fq < 4; ++fq) {
      int r = wm * 64 + fq * 16 + ll;
#pragma unroll
      for (int kk = 0; kk < 2; ++kk) {
        int a = (r * 128 + kk * 64 + lg * 16) ^ ((r & 7) << 4);
        af[fq][kk] = load8((const unsigned short*)(lAc + a));
      }
    }
#pragma unroll
    for (int nh = 0; nh < 2; ++nh)
#pragma unroll
      for (int fq = 0; fq < 2; ++fq) {
        int r = wn * 64 + nh * 32 + fq * 16 + ll;
#pragma unroll
        for (int kk = 0; kk < 2; ++kk) {
          int a = (r * 128 + kk * 64 + lg * 16) ^ ((r & 7) << 4);
          bfr[nh][fq][kk] = load8((const unsigned short*)(lBc + a));
        }
      }

    if (t + 2 < NT) STAGE((t + 2) % 3, t + 2);

    __builtin_amdgcn_s_setprio(1);
#pragma unroll
    for (int nh = 0; nh < 2; ++nh)
#pragma unroll
      for (int fq = 0; fq < 4; ++fq)
#pragma unroll
        for (int gq = 0; gq < 2; ++gq)
#pragma unroll
          for (int kk = 0; kk < 2; ++kk)
            acc[fq][nh * 2 + gq] =
                mfma_bf16(af[fq][kk], bfr[nh][gq][kk], acc[fq][nh * 2 + gq]);
    __builtin_amdgcn_s_setprio(0);

    if (t + 2 < NT)
      asm volatile("s_waitcnt vmcnt(6)" ::: "memory");
    else if (t + 1 < NT)
      asm volatile("s_waitcnt vmcnt(0)" ::: "memory");
    asm volatile("s_barrier" ::: "memory");
  }

  // epilogue: C/D frag layout col = lane&15, row = (lane>>4)*4 + j
#pragma unroll
  for (int fm = 0; fm < 4; ++fm)
#pragma unroll
    for (int fn = 0; fn < 4; ++fn)
#pragma unroll
      for (int j = 0; j < 4; ++j) {
        int r   = m0 + wm * 64 + fm * 16 + lg * 4 + j;
        int col = n0 + wn * 64 + fn * 16 + ll;
        if (OUT_BF16)
          ((unsigned short*)C)[(size_t)r * N + col] = f2bf(acc[fm][fn][j]);
        else
          ((float*)C)[(size_t)r * N + col] = acc[fm][fn][j];
      }
}

// ---------------------------------------------------------------- RoPE q,k
__global__ void rope_qk_kernel(const unsigned short* __restrict__ mixed,
                               const float* __restrict__ cosT,
                               const float* __restrict__ sinT,
                               unsigned short* __restrict__ qr,
                               unsigned short* __restrict__ kr) {
  int m = blockIdx.x;              // 0..BS-1
  int s = m & (S_DIM - 1);
  int b = m >> 11;
  const unsigned short* row = mixed + (size_t)m * O3;
  int t = threadIdx.x;
  int h = t >> 4, dg = (t & 15) << 2;   // d = dg..dg+3
  int base = h * 384;
  s16x4 q0 = *(const s16x4*)(row + base + dg);
  s16x4 q1 = *(const s16x4*)(row + base + 64 + dg);
  s16x4 k0 = *(const s16x4*)(row + base + 128 + dg);
  s16x4 k1 = *(const s16x4*)(row + base + 192 + dg);
  float4 c4 = *(const float4*)(cosT + (s << 6) + dg);
  float4 s4 = *(const float4*)(sinT + (s << 6) + dg);
  size_t ob = ((size_t)(b * NHEAD + h) * S_DIM + s) * HD_DIM;
  s16x4 oq0, oq1, ok0, ok1;
  float cc[4] = {c4.x, c4.y, c4.z, c4.w};
  float ss[4] = {s4.x, s4.y, s4.z, s4.w};
#pragma unroll
  for (int i = 0; i < 4; ++i) {
    float q0f = bf2f((unsigned short)q0[i]), q1f = bf2f((unsigned short)q1[i]);
    float k0f = bf2f((unsigned short)k0[i]), k1f = bf2f((unsigned short)k1[i]);
    oq0[i] = (short)f2bf(q0f * cc[i] - q1f * ss[i]);
    oq1[i] = (short)f2bf(q1f * cc[i] + q0f * ss[i]);
    ok0[i] = (short)f2bf(k0f * cc[i] - k1f * ss[i]);
    ok1[i] = (short)f2bf(k1f * cc[i] + k0f * ss[i]);
  }
  *(s16x4*)(qr + ob + dg)      = oq0;
  *(s16x4*)(qr + ob + 64 + dg) = oq1;
  *(s16x4*)(kr + ob + dg)      = ok0;
  *(s16x4*)(kr + ob + 64 + dg) = ok1;
}

// ---------------------------------------------------------------- V transpose
__global__ __launch_bounds__(256)
void vtrans_kernel(const unsigned short* __restrict__ mixed,
                   unsigned short* __restrict__ vt) {
  __shared__ unsigned short t[64 * 65];
  int st = blockIdx.x, dt = blockIdx.y, bh = blockIdx.z;
  int b = bh >> 4, h = bh & 15;
  int s0 = st * 64, d0 = dt * 64;
  int tid = threadIdx.x;
#pragma unroll
  for (int it = 0; it < 2; ++it) {
    int c = it * 256 + tid;                 // 0..511
    int sl = c >> 3, dc = c & 7;
    const unsigned short* src =
        mixed + (size_t)(b * S_DIM + s0 + sl) * O3 + h * 384 + 256 + d0 + dc * 8;
    s16x8 v = *(const s16x8*)src;
#pragma unroll
    for (int i = 0; i < 8; ++i) t[(dc * 8 + i) * 65 + sl] = (unsigned short)v[i];
  }
  __syncthreads();
#pragma unroll
  for (int it = 0; it < 2; ++it) {
    int c = it * 256 + tid;
    int dl = c >> 3, sc = c & 7;
    s16x8 v;
#pragma unroll
    for (int i = 0; i < 8; ++i) v[i] = (short)t[dl * 65 + sc * 8 + i];
    *(s16x8*)(vt + ((size_t)bh * HD_DIM + d0 + dl) * S_DIM + s0 + sc * 8) = v;
  }
}

// ---------------------------------------------------------------- attention
// 8-wave, KVBLK=128 staging: grid (p=8, bh=32) = 256 blocks, 512 threads,
// 128 q-rows/block. Pairing {p, 15-p}: ntb128 = qt+1 -> 17 kv128-tiles
// (= 34 kv64-halves) EVERY block. Staging calls + barriers HALVED vs r20
// (KVBLK=64): one stage + one __syncthreads per 128 kv rows; each staged
// tile has a full 128-tile compute window of latency cover.
// K tile [128 s][128 d], V tile [128 d][128 s]; both 16 chunks/row with
// involution cs = c ^ ((c>>4)&7); reads XOR ((row&7)<<4) (2-way max).
// Mask window (64-half index th): th >= ntb64-2.
__global__ __launch_bounds__(512, 1)
void attn_kernel(const unsigned short* __restrict__ qr,
                 const unsigned short* __restrict__ kr,
                 const unsigned short* __restrict__ vt,
                 unsigned short* __restrict__ out) {
  __shared__ __align__(16) unsigned short kbuf[2][128 * 128]; // 2 x 32KB
  __shared__ __align__(16) unsigned short vbuf[2][128 * 128]; // 2 x 32KB
  __shared__ __align__(16) unsigned short plds[8][16 * 72];   // 18KB
  const int p = blockIdx.x, bh = blockIdx.y;
  const int wave = threadIdx.x >> 6, lane = threadIdx.x & 63;
  const int b = bh >> 4, h = bh & 15;
  const int lg = lane >> 4, ll = lane & 15;
  const unsigned short* Qb = qr + (size_t)bh * S_DIM * HD_DIM;
  const unsigned short* Kb = kr + (size_t)bh * S_DIM * HD_DIM;
  const unsigned short* Vb = vt + (size_t)bh * HD_DIM * S_DIM;
  const float kE  = 0.12752792f;   // (1/sqrt(128)) * log2(e)
  const float THR = 11.5416f;      // 8 * log2(e)  (T13 threshold, k-domain)
  unsigned short* pw = &plds[wave][0];

  for (int seg = 0; seg < 2; ++seg) {
    const int qt = seg ? (15 - p) : p;         // 128-row q-tile index
    const int qbase = qt * 128 + wave * 16;
    const int ntb = qt + 1;                    // kv128-tile count
    const int ntb64 = 2 * qt + 2;              // kv64-half count

    // stage one 128-row KV tile: K 2048 chunks + V 2048 chunks, 8/thread
    auto STAGE = [&](int buf, int t) {
      const int k0 = t * 128;
#pragma unroll
      for (int i = 0; i < 4; ++i) {
        int cb = (i * 8 + wave) * 64 + lane;   // 0..2047
        int cs = cb ^ ((cb >> 4) & 7);
        gload_lds16(Kb + (size_t)(k0 + (cs >> 4)) * HD_DIM + (cs & 15) * 8,
                    &kbuf[buf][cb * 8]);
      }
#pragma unroll
      for (int i = 0; i < 4; ++i) {
        int cb = (i * 8 + wave) * 64 + lane;
        int cs = cb ^ ((cb >> 4) & 7);
        gload_lds16(Vb + (size_t)(cs >> 4) * S_DIM + k0 + (cs & 15) * 8,
                    &vbuf[buf][cb * 8]);
      }
    };

    bf16x8 aq[4];
#pragma unroll
    for (int kk = 0; kk < 4; ++kk)
      aq[kk] = load8(Qb + (size_t)(qbase + ll) * HD_DIM + kk * 32 + lg * 8);

    float mk[4], lsum[4];
    f32x4 o[8];
#pragma unroll
    for (int j = 0; j < 4; ++j) { mk[j] = -1e30f; lsum[j] = 0.f; }
#pragma unroll
    for (int f = 0; f < 8; ++f) o[f] = (f32x4){0.f, 0.f, 0.f, 0.f};

    STAGE(0, 0);
    __syncthreads();   // implicit vmcnt(0) drain

    for (int t = 0; t < ntb; ++t) {
      const int cur = t & 1;
      if (t + 1 < ntb) STAGE(cur ^ 1, t + 1);  // full-tile latency cover
      const char* kb = (const char*)&kbuf[cur][0];
      const char* vb = (const char*)&vbuf[cur][0];

#pragma unroll
      for (int half = 0; half < 2; ++half) {
        const int th = 2 * t + half;           // kv64-half index
        const int k0h = th * 64;
        const bool maskt = (th >= ntb64 - 2);  // block-uniform

        // ---- QK^T: s[kf] covers kv rows k0h+kf*16..+16
        f32x4 s[4];
#pragma unroll
        for (int kf = 0; kf < 4; ++kf) s[kf] = (f32x4){0.f, 0.f, 0.f, 0.f};
        __builtin_amdgcn_s_setprio(1);
#pragma unroll
        for (int kf = 0; kf < 4; ++kf) {
          int r = half * 64 + kf * 16 + ll;    // row in 128-row K tile
#pragma unroll
          for (int kk = 0; kk < 4; ++kk) {
            int a = (r * 256 + kk * 64 + lg * 16) ^ ((r & 7) << 4);
            s[kf] = mfma_bf16(aq[kk], load8((const unsigned short*)(kb + a)),
                              s[kf]);
          }
        }
        __builtin_amdgcn_s_setprio(0);

        // ---- causal mask (last two 64-halves only)
        if (maskt) {
#pragma unroll
          for (int kf = 0; kf < 4; ++kf) {
            int kcol = k0h + kf * 16 + ll;
#pragma unroll
            for (int j = 0; j < 4; ++j) {
              int qrow = qbase + lg * 4 + j;
              if (kcol > qrow) s[kf][j] = -1e31f;
            }
          }
        }

        // ---- defer-max online softmax (T13). mk is running max * kE.
        float pmax[4];
        bool ok = true;
#pragma unroll
        for (int j = 0; j < 4; ++j) {
          pmax[j] = fmaxf(fmaxf(s[0][j], s[1][j]), fmaxf(s[2][j], s[3][j]));
          ok = ok && (pmax[j] * kE - mk[j] <= THR);
        }
        if (!__all(ok)) {                      // rare: ~once per segment
#pragma unroll
          for (int j = 0; j < 4; ++j) {
            float rm = pmax[j] * kE;
#pragma unroll
            for (int off = 1; off < 16; off <<= 1)
              rm = fmaxf(rm, __shfl_xor(rm, off, 64));
            rm = fmaxf(rm, mk[j]);
            float corr = exp2f(mk[j] - rm);
            mk[j] = rm;
            lsum[j] *= corr;
#pragma unroll
            for (int f = 0; f < 8; ++f) o[f][j] *= corr;
          }
        }
        // P = exp2(s*kE - mk); per-lane l partials.
#pragma unroll
        for (int j = 0; j < 4; ++j) {
          int prow = (lg * 4 + j) * 72;
#pragma unroll
          for (int kf = 0; kf < 4; ++kf) {
            float e = exp2f(fmaf(s[kf][j], kE, -mk[j]));
            lsum[j] += e;
            pw[prow + kf * 16 + ll] = f2bf(e);
          }
        }

        // ---- PV from swizzled V LDS (P round-trip through per-wave LDS)
        bf16x8 pa0 = load8(&pw[ll * 72 + lg * 8]);
        bf16x8 pa1 = load8(&pw[ll * 72 + 32 + lg * 8]);
        __builtin_amdgcn_s_setprio(1);
#pragma unroll
        for (int f = 0; f < 8; ++f) {
          int rv = f * 16 + ll;                // d-row in 128-row V tile
          int a0 = (rv * 256 + half * 128 + lg * 16) ^ ((rv & 7) << 4);
          int a1 = (rv * 256 + half * 128 + 64 + lg * 16) ^ ((rv & 7) << 4);
          o[f] = mfma_bf16(pa0, load8((const unsigned short*)(vb + a0)), o[f]);
          o[f] = mfma_bf16(pa1, load8((const unsigned short*)(vb + a1)), o[f]);
        }
        __builtin_amdgcn_s_setprio(0);
      }

      __syncthreads();   // once per 128-tile: drains staged vmcnt + dbuf guard
    }

    // ---- epilogue: reduce l partials once, normalize, store
#pragma unroll
    for (int j = 0; j < 4; ++j) {
      float l = lsum[j];
#pragma unroll
      for (int off = 1; off < 16; off <<= 1) l += __shfl_xor(l, off, 64);
      lsum[j] = 1.0f / l;
    }
#pragma unroll
    for (int f = 0; f < 8; ++f)
#pragma unroll
      for (int j = 0; j < 4; ++j) {
        int srow = qbase + lg * 4 + j;
        out[((size_t)(b * S_DIM + srow)) * H_DIM + h * HD_DIM + f * 16 + ll] =
            f2bf(o[f][j] * lsum[j]);
      }
  }
}

// ---------------------------------------------------------------- launch
extern "C" void kernel_launch(void* const* d_in, const int* in_sizes, int n_in,
                              void* d_out, int out_size, void* d_ws, size_t ws_size,
                              hipStream_t stream) {
  (void)in_sizes; (void)n_in; (void)out_size; (void)ws_size;
  const float* hidden = (const float*)d_in[0];
  const float* wqkv   = (const float*)d_in[1];
  const float* wo     = (const float*)d_in[2];
  char* ws = (char*)d_ws;
  unsigned short* hid_b  = (unsigned short*)(ws);               // 16,777,216
  unsigned short* wqkv_b = (unsigned short*)(ws + 16777216);    // 25,165,824
  unsigned short* wo_b   = (unsigned short*)(ws + 41943040);    //  8,388,608
  unsigned short* mixed  = (unsigned short*)(ws + 50331648);    // 50,331,648
  unsigned short* q_r    = (unsigned short*)(ws + 100663296);   // 16,777,216
  unsigned short* k_r    = (unsigned short*)(ws + 117440512);   // 16,777,216
  unsigned short* v_t    = (unsigned short*)(ws + 134217728);   // 16,777,216
  unsigned short* attn   = (unsigned short*)(ws + 150994944);   // 16,777,216
  float* cosT            = (float*)(ws + 167772160);            //    524,288
  float* sinT            = (float*)(ws + 168296448);            //    524,288

  prep_kernel<<<2048, 256, 0, stream>>>(hidden, wqkv, wo, hid_b, wqkv_b, wo_b,
                                        cosT, sinT);

  // QKV projection: grid 24x32 = 768 = exactly 3 rounds; L2-aware XCD map
  gemm3b_kernel<true, true><<<dim3(O3 / 256, BS / 128), 512, 0, stream>>>(
      hid_b, wqkv_b, mixed, BS, O3, H_DIM);

  rope_qk_kernel<<<BS, 256, 0, stream>>>(mixed, cosT, sinT, q_r, k_r);
  vtrans_kernel<<<dim3(32, 2, 32), 256, 0, stream>>>(mixed, v_t);

  // attention: 8-wave blocks, KVBLK=128 staging, grid 8x32 = 256 = 1/CU
  attn_kernel<<<dim3(8, 32), 512, 0, stream>>>(q_r, k_r, v_t, attn);

  // output projection: grid 8x32 = 256 = exactly 1 round; chunked map
  gemm3b_kernel<false, false><<<dim3(H_DIM / 256, BS / 128), 512, 0, stream>>>(
      attn, wo_b, d_out, BS, H_DIM, H_DIM);
}

// Round 23
// 254.166 us; speedup vs baseline: 1.1173x; 1.0420x over previous
//
#include <hip/hip_runtime.h>
#include <hip/hip_bf16.h>
#include <cstdint>
#include <cstddef>

// Problem constants
#define S_DIM 2048
#define H_DIM 2048
#define NHEAD 16
#define HD_DIM 128
#define O3    6144   // 3*H
#define BS    4096   // B*S
#define NBH   32     // B*NHEAD

typedef short  s16x4  __attribute__((ext_vector_type(4)));
typedef short  s16x8  __attribute__((ext_vector_type(8)));
typedef __bf16 bf16x8 __attribute__((ext_vector_type(8)));
typedef float  f32x4  __attribute__((ext_vector_type(4)));

__device__ __forceinline__ unsigned short f2bf(float f) {
  unsigned int b = __float_as_uint(f);
  b += 0x7FFFu + ((b >> 16) & 1u);          // round-to-nearest-even
  return (unsigned short)(b >> 16);
}
__device__ __forceinline__ float bf2f(unsigned short u) {
  return __uint_as_float(((unsigned int)u) << 16);
}
__device__ __forceinline__ bf16x8 load8(const unsigned short* p) {
  s16x8 r = *(const s16x8*)p;
  return __builtin_bit_cast(bf16x8, r);
}
__device__ __forceinline__ f32x4 mfma_bf16(bf16x8 a, bf16x8 b, f32x4 c) {
  return __builtin_amdgcn_mfma_f32_16x16x32_bf16(a, b, c, 0, 0, 0);
}
__device__ __forceinline__ void gload_lds16(const void* g, void* l) {
  __builtin_amdgcn_global_load_lds(
      (__attribute__((address_space(1))) unsigned int*)g,
      (__attribute__((address_space(3))) unsigned int*)l, 16, 0, 0);
}

// -------------------------------------------------- fused prep (one launch)
__global__ void prep_kernel(const float* __restrict__ hid,
                            const float* __restrict__ wqkv,
                            const float* __restrict__ wo,
                            unsigned short* __restrict__ hid_b,
                            unsigned short* __restrict__ wqkv_b,
                            unsigned short* __restrict__ wo_b,
                            float* __restrict__ cosT,
                            float* __restrict__ sinT) {
  const int nA = 2097152, nB = 3145728, nC = 1048576, nD = 131072;
  const int total = nA + nB + nC + nD;
  int stride = gridDim.x * blockDim.x;
  for (int i = blockIdx.x * blockDim.x + threadIdx.x; i < total; i += stride) {
    if (i < nA + nB + nC) {
      const float* src; unsigned short* dst; int j;
      if (i < nA)            { src = hid;  dst = hid_b;  j = i; }
      else if (i < nA + nB)  { src = wqkv; dst = wqkv_b; j = i - nA; }
      else                   { src = wo;   dst = wo_b;   j = i - nA - nB; }
      float4 v = ((const float4*)src)[j];
      ushort4 o;
      o.x = f2bf(v.x); o.y = f2bf(v.y); o.z = f2bf(v.z); o.w = f2bf(v.w);
      ((ushort4*)dst)[j] = o;
    } else {
      int idx = i - nA - nB - nC;          // 0..131071 = s*64 + d
      int s = idx >> 6, d = idx & 63;
      float inv = expf(-((float)d / 64.0f) * 9.210340371976184f);
      float ang = (float)s * inv;
      float sn, cs;
      sincosf(ang, &sn, &cs);
      cosT[idx] = cs;
      sinT[idx] = sn;
    }
  }
}

// ------------------------------------- QKV GEMM with fused RoPE epilogue
// Mainloop = proven gemm3b (BM=128,BN=256,BK=64, 3buf, vmcnt(6), 116us/38%).
// Epilogue: each wave's 64-col window is one sub-block of the 384-per-head
// QKV layout: g = n_tile*4+wn, sub=g%6 in {q-lo,q-hi,k-lo,k-hi,v-lo,v-hi},
// h=g/6. RoPE pairs (lo,hi) are ALWAYS partner wave = wave^1 in-block
// (lo-blocks land at even wn since 6%2==0). Exchange acc via LDS (reuse
// staging buffers after the final barrier; [idx][lane] layout = conflict-
// free), rotate with cos/sin table in f32, write q_r/k_r directly.
// V-waves write compact vc[row][h*128+d]. Saves the entire rope_qk kernel
// (67MB read + 67MB write + launch).
__global__ __launch_bounds__(512, 1)
void gemm_qkv_kernel(const unsigned short* __restrict__ A,
                     const unsigned short* __restrict__ Bw,
                     unsigned short* __restrict__ q_r,
                     unsigned short* __restrict__ k_r,
                     unsigned short* __restrict__ vc,
                     const float* __restrict__ cosT,
                     const float* __restrict__ sinT,
                     int M, int N, int K) {
  __shared__ __align__(16) unsigned short lA[3][128 * 64];   // 3 x 16KB
  __shared__ __align__(16) unsigned short lB[3][256 * 64];   // 3 x 32KB
  const int tid  = threadIdx.x;
  const int wave = tid >> 6, lane = tid & 63;
  const int wm = wave >> 2, wn = wave & 3;       // 2M x 4N wave grid
  const int lg = lane >> 4, ll = lane & 15;

  // L2-aware XCD map (r11): grid 24(n) x 32(m)
  const int nbx = gridDim.x;
  const int id  = blockIdx.y * nbx + blockIdx.x;
  const int k8 = id & 7, q8 = id >> 3;
  const int ng = q8 >> 5, r8 = q8 & 31;
  const int m_tile = (k8 >> 1) * 8 + (r8 & 7);
  const int n_tile = (k8 & 1) * 12 + ng * 4 + (r8 >> 3);
  const int m0 = m_tile * 128, n0 = n_tile * 256;

  f32x4 acc[4][4];
#pragma unroll
  for (int i = 0; i < 4; ++i)
#pragma unroll
    for (int j = 0; j < 4; ++j) acc[i][j] = (f32x4){0.f, 0.f, 0.f, 0.f};

  const unsigned short* aP[2];
  const unsigned short* bP[4];
  int aD[2], bD[4];
#pragma unroll
  for (int i = 0; i < 2; ++i) {
    int cb = (i * 8 + wave) * 64 + lane;
    int cs = cb ^ ((cb >> 3) & 7);
    aP[i] = A + (size_t)(m0 + (cs >> 3)) * K + (cs & 7) * 8;
    aD[i] = cb * 8;
  }
#pragma unroll
  for (int i = 0; i < 4; ++i) {
    int cb = (i * 8 + wave) * 64 + lane;
    int cs = cb ^ ((cb >> 3) & 7);
    bP[i] = Bw + (size_t)(n0 + (cs >> 3)) * K + (cs & 7) * 8;
    bD[i] = cb * 8;
  }

  auto STAGE = [&](int buf, int t) {
    const int kt = t << 6;
#pragma unroll
    for (int i = 0; i < 2; ++i) gload_lds16(aP[i] + kt, &lA[buf][aD[i]]);
#pragma unroll
    for (int i = 0; i < 4; ++i) gload_lds16(bP[i] + kt, &lB[buf][bD[i]]);
  };

  const int NT = K >> 6;
  STAGE(0, 0);
  STAGE(1, 1);
  asm volatile("s_waitcnt vmcnt(6)" ::: "memory");
  asm volatile("s_barrier" ::: "memory");

  for (int t = 0; t < NT; ++t) {
    const int cur = t % 3;
    const char* lAc = (const char*)&lA[cur][0];
    const char* lBc = (const char*)&lB[cur][0];

    bf16x8 af[4][2], bfr[2][2][2];
#pragma unroll
    for (int fq = 0; fq < 4; ++fq) {
      int r = wm * 64 + fq * 16 + ll;
#pragma unroll
      for (int kk = 0; kk < 2; ++kk) {
        int a = (r * 128 + kk * 64 + lg * 16) ^ ((r & 7) << 4);
        af[fq][kk] = load8((const unsigned short*)(lAc + a));
      }
    }
#pragma unroll
    for (int nh = 0; nh < 2; ++nh)
#pragma unroll
      for (int fq = 0; fq < 2; ++fq) {
        int r = wn * 64 + nh * 32 + fq * 16 + ll;
#pragma unroll
        for (int kk = 0; kk < 2; ++kk) {
          int a = (r * 128 + kk * 64 + lg * 16) ^ ((r & 7) << 4);
          bfr[nh][fq][kk] = load8((const unsigned short*)(lBc + a));
        }
      }

    if (t + 2 < NT) STAGE((t + 2) % 3, t + 2);

    __builtin_amdgcn_s_setprio(1);
#pragma unroll
    for (int nh = 0; nh < 2; ++nh)
#pragma unroll
      for (int fq = 0; fq < 4; ++fq)
#pragma unroll
        for (int gq = 0; gq < 2; ++gq)
#pragma unroll
          for (int kk = 0; kk < 2; ++kk)
            acc[fq][nh * 2 + gq] =
                mfma_bf16(af[fq][kk], bfr[nh][gq][kk], acc[fq][nh * 2 + gq]);
    __builtin_amdgcn_s_setprio(0);

    if (t + 2 < NT)
      asm volatile("s_waitcnt vmcnt(6)" ::: "memory");
    else if (t + 1 < NT)
      asm volatile("s_waitcnt vmcnt(0)" ::: "memory");
    asm volatile("s_barrier" ::: "memory");
  }

  // ---- fused RoPE epilogue (after final barrier: LDS reuse is safe) ----
  const int g   = n_tile * 4 + wn;
  const int sub = g % 6, hh = g / 6;
  // slot(w): 16KB per wave carved from the staging buffers
  float* slot = (wave < 3) ? (float*)&lA[wave][0]
                           : (float*)&lB[0][0] + (size_t)(wave - 3) * 4096;
  const float* pslot = ((wave ^ 1) < 3)
                           ? (const float*)&lA[wave ^ 1][0]
                           : (const float*)&lB[0][0] + (size_t)((wave ^ 1) - 3) * 4096;
  // write own acc: [idx][lane] layout -> conflict-free
#pragma unroll
  for (int fm = 0; fm < 4; ++fm)
#pragma unroll
    for (int fn = 0; fn < 4; ++fn)
#pragma unroll
      for (int j = 0; j < 4; ++j)
        slot[(fm * 16 + fn * 4 + j) * 64 + lane] = acc[fm][fn][j];
  __syncthreads();

  if (sub < 4) {
    // q/k with RoPE: lo (sub even): out = a*c - p*s ; hi: out = a*c + p*s
    const bool hi = (sub & 1);
    unsigned short* dst = (sub < 2) ? q_r : k_r;
    const int dbase = hi ? 64 : 0;
#pragma unroll
    for (int fm = 0; fm < 4; ++fm)
#pragma unroll
      for (int fn = 0; fn < 4; ++fn)
#pragma unroll
        for (int j = 0; j < 4; ++j) {
          int r  = m0 + wm * 64 + fm * 16 + lg * 4 + j;
          int s  = r & (S_DIM - 1), bb = r >> 11;
          int dp = fn * 16 + ll;
          float c  = cosT[(s << 6) + dp];
          float sn = sinT[(s << 6) + dp];
          float a  = acc[fm][fn][j];
          float pv = pslot[(fm * 16 + fn * 4 + j) * 64 + lane];
          float ov = hi ? fmaf(a, c, pv * sn) : fmaf(a, c, -pv * sn);
          size_t ob = ((size_t)(bb * NHEAD + hh) * S_DIM + s) * HD_DIM
                      + dbase + dp;
          dst[ob] = f2bf(ov);
        }
  } else {
    // v: compact layout vc[row][h*128 + d], d = (sub-4)*64 + dp
    const int dbase = (sub - 4) * 64;
#pragma unroll
    for (int fm = 0; fm < 4; ++fm)
#pragma unroll
      for (int fn = 0; fn < 4; ++fn)
#pragma unroll
        for (int j = 0; j < 4; ++j) {
          int r  = m0 + wm * 64 + fm * 16 + lg * 4 + j;
          int dp = fn * 16 + ll;
          vc[(size_t)r * H_DIM + hh * HD_DIM + dbase + dp] =
              f2bf(acc[fm][fn][j]);
        }
  }
}

// ------------------------------------------------- triple-buffered GEMM (B^T)
// Kept for the output projection (256 blocks = exactly 1 round there).
template <bool OUT_BF16, bool QKV_MAP>
__global__ __launch_bounds__(512, 1)
void gemm3b_kernel(const unsigned short* __restrict__ A,
                   const unsigned short* __restrict__ Bw,
                   void* __restrict__ C, int M, int N, int K) {
  __shared__ __align__(16) unsigned short lA[3][128 * 64];   // 3 x 16KB
  __shared__ __align__(16) unsigned short lB[3][256 * 64];   // 3 x 32KB
  const int tid  = threadIdx.x;
  const int wave = tid >> 6, lane = tid & 63;
  const int wm = wave >> 2, wn = wave & 3;       // 2M x 4N wave grid
  const int lg = lane >> 4, ll = lane & 15;

  const int nbx = gridDim.x;
  const int id  = blockIdx.y * nbx + blockIdx.x;
  int m_tile, n_tile;
  if (QKV_MAP) {
    const int k = id & 7, q = id >> 3;
    const int ng = q >> 5, r = q & 31;
    m_tile = (k >> 1) * 8 + (r & 7);
    n_tile = (k & 1) * 12 + ng * 4 + (r >> 3);
  } else {
    const int nwg = gridDim.x * gridDim.y;
    const int swz = (id & 7) * (nwg >> 3) + (id >> 3);
    m_tile = swz / nbx;
    n_tile = swz % nbx;
  }
  const int m0 = m_tile * 128, n0 = n_tile * 256;

  f32x4 acc[4][4];
#pragma unroll
  for (int i = 0; i < 4; ++i)
#pragma unroll
    for (int j = 0; j < 4; ++j) acc[i][j] = (f32x4){0.f, 0.f, 0.f, 0.f};

  const unsigned short* aP[2];
  const unsigned short* bP[4];
  int aD[2], bD[4];
#pragma unroll
  for (int i = 0; i < 2; ++i) {
    int cb = (i * 8 + wave) * 64 + lane;
    int cs = cb ^ ((cb >> 3) & 7);
    aP[i] = A + (size_t)(m0 + (cs >> 3)) * K + (cs & 7) * 8;
    aD[i] = cb * 8;
  }
#pragma unroll
  for (int i = 0; i < 4; ++i) {
    int cb = (i * 8 + wave) * 64 + lane;
    int cs = cb ^ ((cb >> 3) & 7);
    bP[i] = Bw + (size_t)(n0 + (cs >> 3)) * K + (cs & 7) * 8;
    bD[i] = cb * 8;
  }

  auto STAGE = [&](int buf, int t) {
    const int kt = t << 6;
#pragma unroll
    for (int i = 0; i < 2; ++i) gload_lds16(aP[i] + kt, &lA[buf][aD[i]]);
#pragma unroll
    for (int i = 0; i < 4; ++i) gload_lds16(bP[i] + kt, &lB[buf][bD[i]]);
  };

  const int NT = K >> 6;
  STAGE(0, 0);
  if (NT > 1) {
    STAGE(1, 1);
    asm volatile("s_waitcnt vmcnt(6)" ::: "memory");
  } else {
    asm volatile("s_waitcnt vmcnt(0)" ::: "memory");
  }
  asm volatile("s_barrier" ::: "memory");

  for (int t = 0; t < NT; ++t) {
    const int cur = t % 3;
    const char* lAc = (const char*)&lA[cur][0];
    const char* lBc = (const char*)&lB[cur][0];

    bf16x8 af[4][2], bfr[2][2][2];
#pragma unroll
    for (int fq = 0; fq < 4; ++fq) {
      int r = wm * 64 + fq * 16 + ll;
#pragma unroll
      for (int kk = 0; kk < 2; ++kk) {
        int a = (r * 128 + kk * 64 + lg * 16) ^ ((r & 7) << 4);
        af[fq][kk] = load8((const unsigned short*)(lAc + a));
      }
    }
#pragma unroll
    for (int nh = 0; nh < 2; ++nh)
#pragma unroll
      for (int fq = 0; fq < 2; ++fq) {
        int r = wn * 64 + nh * 32 + fq * 16 + ll;
#pragma unroll
        for (int kk = 0; kk < 2; ++kk) {
          int a = (r * 128 + kk * 64 + lg * 16) ^ ((r & 7) << 4);
          bfr[nh][fq][kk] = load8((const unsigned short*)(lBc + a));
        }
      }

    if (t + 2 < NT) STAGE((t + 2) % 3, t + 2);

    __builtin_amdgcn_s_setprio(1);
#pragma unroll
    for (int nh = 0; nh < 2; ++nh)
#pragma unroll
      for (int fq = 0; fq < 4; ++fq)
#pragma unroll
        for (int gq = 0; gq < 2; ++gq)
#pragma unroll
          for (int kk = 0; kk < 2; ++kk)
            acc[fq][nh * 2 + gq] =
                mfma_bf16(af[fq][kk], bfr[nh][gq][kk], acc[fq][nh * 2 + gq]);
    __builtin_amdgcn_s_setprio(0);

    if (t + 2 < NT)
      asm volatile("s_waitcnt vmcnt(6)" ::: "memory");
    else if (t + 1 < NT)
      asm volatile("s_waitcnt vmcnt(0)" ::: "memory");
    asm volatile("s_barrier" ::: "memory");
  }

#pragma unroll
  for (int fm = 0; fm < 4; ++fm)
#pragma unroll
    for (int fn = 0; fn < 4; ++fn)
#pragma unroll
      for (int j = 0; j < 4; ++j) {
        int r   = m0 + wm * 64 + fm * 16 + lg * 4 + j;
        int col = n0 + wn * 64 + fn * 16 + ll;
        if (OUT_BF16)
          ((unsigned short*)C)[(size_t)r * N + col] = f2bf(acc[fm][fn][j]);
        else
          ((float*)C)[(size_t)r * N + col] = acc[fm][fn][j];
      }
}

// ---------------------------------------------------------------- V transpose
// v_t[bh][d][s] <- vc[b*S+s][h*128+d] (compact layout); 64x64 tiles via LDS.
__global__ __launch_bounds__(256)
void vtrans_kernel(const unsigned short* __restrict__ vc,
                   unsigned short* __restrict__ vt) {
  __shared__ unsigned short t[64 * 65];
  int st = blockIdx.x, dt = blockIdx.y, bh = blockIdx.z;
  int b = bh >> 4, h = bh & 15;
  int s0 = st * 64, d0 = dt * 64;
  int tid = threadIdx.x;
#pragma unroll
  for (int it = 0; it < 2; ++it) {
    int c = it * 256 + tid;                 // 0..511
    int sl = c >> 3, dc = c & 7;
    const unsigned short* src =
        vc + (size_t)(b * S_DIM + s0 + sl) * H_DIM + h * HD_DIM + d0 + dc * 8;
    s16x8 v = *(const s16x8*)src;
#pragma unroll
    for (int i = 0; i < 8; ++i) t[(dc * 8 + i) * 65 + sl] = (unsigned short)v[i];
  }
  __syncthreads();
#pragma unroll
  for (int it = 0; it < 2; ++it) {
    int c = it * 256 + tid;
    int dl = c >> 3, sc = c & 7;
    s16x8 v;
#pragma unroll
    for (int i = 0; i < 8; ++i) v[i] = (short)t[dl * 65 + sc * 8 + i];
    *(s16x8*)(vt + ((size_t)bh * HD_DIM + d0 + dl) * S_DIM + s0 + sc * 8) = v;
  }
}

// ---------------------------------------------------------------- attention
// 8-wave, KVBLK=128 staging (r22): grid (p=8, bh=32), 512 threads,
// 128 q-rows/block; pairing {p, 15-p} -> 17 kv128-tiles every block.
__global__ __launch_bounds__(512, 1)
void attn_kernel(const unsigned short* __restrict__ qr,
                 const unsigned short* __restrict__ kr,
                 const unsigned short* __restrict__ vt,
                 unsigned short* __restrict__ out) {
  __shared__ __align__(16) unsigned short kbuf[2][128 * 128]; // 2 x 32KB
  __shared__ __align__(16) unsigned short vbuf[2][128 * 128]; // 2 x 32KB
  __shared__ __align__(16) unsigned short plds[8][16 * 72];   // 18KB
  const int p = blockIdx.x, bh = blockIdx.y;
  const int wave = threadIdx.x >> 6, lane = threadIdx.x & 63;
  const int b = bh >> 4, h = bh & 15;
  const int lg = lane >> 4, ll = lane & 15;
  const unsigned short* Qb = qr + (size_t)bh * S_DIM * HD_DIM;
  const unsigned short* Kb = kr + (size_t)bh * S_DIM * HD_DIM;
  const unsigned short* Vb = vt + (size_t)bh * HD_DIM * S_DIM;
  const float kE  = 0.12752792f;   // (1/sqrt(128)) * log2(e)
  const float THR = 11.5416f;      // 8 * log2(e)  (T13 threshold, k-domain)
  unsigned short* pw = &plds[wave][0];

  for (int seg = 0; seg < 2; ++seg) {
    const int qt = seg ? (15 - p) : p;         // 128-row q-tile index
    const int qbase = qt * 128 + wave * 16;
    const int ntb = qt + 1;                    // kv128-tile count
    const int ntb64 = 2 * qt + 2;              // kv64-half count

    auto STAGE = [&](int buf, int t) {
      const int k0 = t * 128;
#pragma unroll
      for (int i = 0; i < 4; ++i) {
        int cb = (i * 8 + wave) * 64 + lane;   // 0..2047
        int cs = cb ^ ((cb >> 4) & 7);
        gload_lds16(Kb + (size_t)(k0 + (cs >> 4)) * HD_DIM + (cs & 15) * 8,
                    &kbuf[buf][cb * 8]);
      }
#pragma unroll
      for (int i = 0; i < 4; ++i) {
        int cb = (i * 8 + wave) * 64 + lane;
        int cs = cb ^ ((cb >> 4) & 7);
        gload_lds16(Vb + (size_t)(cs >> 4) * S_DIM + k0 + (cs & 15) * 8,
                    &vbuf[buf][cb * 8]);
      }
    };

    bf16x8 aq[4];
#pragma unroll
    for (int kk = 0; kk < 4; ++kk)
      aq[kk] = load8(Qb + (size_t)(qbase + ll) * HD_DIM + kk * 32 + lg * 8);

    float mk[4], lsum[4];
    f32x4 o[8];
#pragma unroll
    for (int j = 0; j < 4; ++j) { mk[j] = -1e30f; lsum[j] = 0.f; }
#pragma unroll
    for (int f = 0; f < 8; ++f) o[f] = (f32x4){0.f, 0.f, 0.f, 0.f};

    STAGE(0, 0);
    __syncthreads();   // implicit vmcnt(0) drain

    for (int t = 0; t < ntb; ++t) {
      const int cur = t & 1;
      if (t + 1 < ntb) STAGE(cur ^ 1, t + 1);  // full-tile latency cover
      const char* kb = (const char*)&kbuf[cur][0];
      const char* vb = (const char*)&vbuf[cur][0];

#pragma unroll
      for (int half = 0; half < 2; ++half) {
        const int th = 2 * t + half;           // kv64-half index
        const int k0h = th * 64;
        const bool maskt = (th >= ntb64 - 2);  // block-uniform

        f32x4 s[4];
#pragma unroll
        for (int kf = 0; kf < 4; ++kf) s[kf] = (f32x4){0.f, 0.f, 0.f, 0.f};
        __builtin_amdgcn_s_setprio(1);
#pragma unroll
        for (int kf = 0; kf < 4; ++kf) {
          int r = half * 64 + kf * 16 + ll;    // row in 128-row K tile
#pragma unroll
          for (int kk = 0; kk < 4; ++kk) {
            int a = (r * 256 + kk * 64 + lg * 16) ^ ((r & 7) << 4);
            s[kf] = mfma_bf16(aq[kk], load8((const unsigned short*)(kb + a)),
                              s[kf]);
          }
        }
        __builtin_amdgcn_s_setprio(0);

        if (maskt) {
#pragma unroll
          for (int kf = 0; kf < 4; ++kf) {
            int kcol = k0h + kf * 16 + ll;
#pragma unroll
            for (int j = 0; j < 4; ++j) {
              int qrow = qbase + lg * 4 + j;
              if (kcol > qrow) s[kf][j] = -1e31f;
            }
          }
        }

        float pmax[4];
        bool ok = true;
#pragma unroll
        for (int j = 0; j < 4; ++j) {
          pmax[j] = fmaxf(fmaxf(s[0][j], s[1][j]), fmaxf(s[2][j], s[3][j]));
          ok = ok && (pmax[j] * kE - mk[j] <= THR);
        }
        if (!__all(ok)) {                      // rare: ~once per segment
#pragma unroll
          for (int j = 0; j < 4; ++j) {
            float rm = pmax[j] * kE;
#pragma unroll
            for (int off = 1; off < 16; off <<= 1)
              rm = fmaxf(rm, __shfl_xor(rm, off, 64));
            rm = fmaxf(rm, mk[j]);
            float corr = exp2f(mk[j] - rm);
            mk[j] = rm;
            lsum[j] *= corr;
#pragma unroll
            for (int f = 0; f < 8; ++f) o[f][j] *= corr;
          }
        }
#pragma unroll
        for (int j = 0; j < 4; ++j) {
          int prow = (lg * 4 + j) * 72;
#pragma unroll
          for (int kf = 0; kf < 4; ++kf) {
            float e = exp2f(fmaf(s[kf][j], kE, -mk[j]));
            lsum[j] += e;
            pw[prow + kf * 16 + ll] = f2bf(e);
          }
        }

        bf16x8 pa0 = load8(&pw[ll * 72 + lg * 8]);
        bf16x8 pa1 = load8(&pw[ll * 72 + 32 + lg * 8]);
        __builtin_amdgcn_s_setprio(1);
#pragma unroll
        for (int f = 0; f < 8; ++f) {
          int rv = f * 16 + ll;                // d-row in 128-row V tile
          int a0 = (rv * 256 + half * 128 + lg * 16) ^ ((rv & 7) << 4);
          int a1 = (rv * 256 + half * 128 + 64 + lg * 16) ^ ((rv & 7) << 4);
          o[f] = mfma_bf16(pa0, load8((const unsigned short*)(vb + a0)), o[f]);
          o[f] = mfma_bf16(pa1, load8((const unsigned short*)(vb + a1)), o[f]);
        }
        __builtin_amdgcn_s_setprio(0);
      }

      __syncthreads();   // once per 128-tile: drains staged vmcnt + dbuf guard
    }

#pragma unroll
    for (int j = 0; j < 4; ++j) {
      float l = lsum[j];
#pragma unroll
      for (int off = 1; off < 16; off <<= 1) l += __shfl_xor(l, off, 64);
      lsum[j] = 1.0f / l;
    }
#pragma unroll
    for (int f = 0; f < 8; ++f)
#pragma unroll
      for (int j = 0; j < 4; ++j) {
        int srow = qbase + lg * 4 + j;
        out[((size_t)(b * S_DIM + srow)) * H_DIM + h * HD_DIM + f * 16 + ll] =
            f2bf(o[f][j] * lsum[j]);
      }
  }
}

// ---------------------------------------------------------------- launch
extern "C" void kernel_launch(void* const* d_in, const int* in_sizes, int n_in,
                              void* d_out, int out_size, void* d_ws, size_t ws_size,
                              hipStream_t stream) {
  (void)in_sizes; (void)n_in; (void)out_size; (void)ws_size;
  const float* hidden = (const float*)d_in[0];
  const float* wqkv   = (const float*)d_in[1];
  const float* wo     = (const float*)d_in[2];
  char* ws = (char*)d_ws;
  unsigned short* hid_b  = (unsigned short*)(ws);               // 16,777,216
  unsigned short* wqkv_b = (unsigned short*)(ws + 16777216);    // 25,165,824
  unsigned short* wo_b   = (unsigned short*)(ws + 41943040);    //  8,388,608
  unsigned short* vc     = (unsigned short*)(ws + 50331648);    // 16,777,216 (compact V)
  unsigned short* q_r    = (unsigned short*)(ws + 100663296);   // 16,777,216
  unsigned short* k_r    = (unsigned short*)(ws + 117440512);   // 16,777,216
  unsigned short* v_t    = (unsigned short*)(ws + 134217728);   // 16,777,216
  unsigned short* attn   = (unsigned short*)(ws + 150994944);   // 16,777,216
  float* cosT            = (float*)(ws + 167772160);            //    524,288
  float* sinT            = (float*)(ws + 168296448);            //    524,288

  prep_kernel<<<2048, 256, 0, stream>>>(hidden, wqkv, wo, hid_b, wqkv_b, wo_b,
                                        cosT, sinT);

  // QKV projection + fused RoPE epilogue: grid 24x32 = 768 = 3 rounds
  gemm_qkv_kernel<<<dim3(O3 / 256, BS / 128), 512, 0, stream>>>(
      hid_b, wqkv_b, q_r, k_r, vc, cosT, sinT, BS, O3, H_DIM);

  vtrans_kernel<<<dim3(32, 2, 32), 256, 0, stream>>>(vc, v_t);

  // attention: 8-wave blocks, KVBLK=128 staging, grid 8x32 = 256 = 1/CU
  attn_kernel<<<dim3(8, 32), 512, 0, stream>>>(q_r, k_r, v_t, attn);

  // output projection: grid 8x32 = 256 = exactly 1 round; chunked map
  gemm3b_kernel<false, false><<<dim3(H_DIM / 256, BS / 128), 512, 0, stream>>>(
      attn, wo_b, d_out, BS, H_DIM, H_DIM);
}

// Round 24
// 246.414 us; speedup vs baseline: 1.1525x; 1.0315x over previous
//
#include <hip/hip_runtime.h>
#include <hip/hip_bf16.h>
#include <cstdint>
#include <cstddef>

// Problem constants
#define S_DIM 2048
#define H_DIM 2048
#define NHEAD 16
#define HD_DIM 128
#define O3    6144   // 3*H
#define BS    4096   // B*S
#define NBH   32     // B*NHEAD

typedef short  s16x4  __attribute__((ext_vector_type(4)));
typedef short  s16x8  __attribute__((ext_vector_type(8)));
typedef __bf16 bf16x8 __attribute__((ext_vector_type(8)));
typedef float  f32x4  __attribute__((ext_vector_type(4)));

__device__ __forceinline__ unsigned short f2bf(float f) {
  unsigned int b = __float_as_uint(f);
  b += 0x7FFFu + ((b >> 16) & 1u);          // round-to-nearest-even
  return (unsigned short)(b >> 16);
}
__device__ __forceinline__ float bf2f(unsigned short u) {
  return __uint_as_float(((unsigned int)u) << 16);
}
__device__ __forceinline__ bf16x8 load8(const unsigned short* p) {
  s16x8 r = *(const s16x8*)p;
  return __builtin_bit_cast(bf16x8, r);
}
__device__ __forceinline__ f32x4 mfma_bf16(bf16x8 a, bf16x8 b, f32x4 c) {
  return __builtin_amdgcn_mfma_f32_16x16x32_bf16(a, b, c, 0, 0, 0);
}
__device__ __forceinline__ void gload_lds16(const void* g, void* l) {
  __builtin_amdgcn_global_load_lds(
      (__attribute__((address_space(1))) unsigned int*)g,
      (__attribute__((address_space(3))) unsigned int*)l, 16, 0, 0);
}

// -------------------------------------------------- fused prep (one launch)
__global__ void prep_kernel(const float* __restrict__ hid,
                            const float* __restrict__ wqkv,
                            const float* __restrict__ wo,
                            unsigned short* __restrict__ hid_b,
                            unsigned short* __restrict__ wqkv_b,
                            unsigned short* __restrict__ wo_b,
                            float* __restrict__ cosT,
                            float* __restrict__ sinT) {
  const int nA = 2097152, nB = 3145728, nC = 1048576, nD = 131072;
  const int total = nA + nB + nC + nD;
  int stride = gridDim.x * blockDim.x;
  for (int i = blockIdx.x * blockDim.x + threadIdx.x; i < total; i += stride) {
    if (i < nA + nB + nC) {
      const float* src; unsigned short* dst; int j;
      if (i < nA)            { src = hid;  dst = hid_b;  j = i; }
      else if (i < nA + nB)  { src = wqkv; dst = wqkv_b; j = i - nA; }
      else                   { src = wo;   dst = wo_b;   j = i - nA - nB; }
      float4 v = ((const float4*)src)[j];
      ushort4 o;
      o.x = f2bf(v.x); o.y = f2bf(v.y); o.z = f2bf(v.z); o.w = f2bf(v.w);
      ((ushort4*)dst)[j] = o;
    } else {
      int idx = i - nA - nB - nC;          // 0..131071 = s*64 + d
      int s = idx >> 6, d = idx & 63;
      float inv = expf(-((float)d / 64.0f) * 9.210340371976184f);
      float ang = (float)s * inv;
      float sn, cs;
      sincosf(ang, &sn, &cs);
      cosT[idx] = cs;
      sinT[idx] = sn;
    }
  }
}

// ------------------------------------- QKV GEMM with fused RoPE epilogue
// Mainloop = proven gemm3b. Fragment addressing HOISTED: since fq*16 == 0
// mod 8, r&7 = ll&7 is fragment-invariant, and the XOR (bits 4-6) is
// disjoint from the fragment deltas fq*2048/nh*4096 (bits >= 11), so
// addr = laneBase[kk] + const  ->  ds_read immediate offsets, ~4 VALU/tile
// instead of ~50 (r23: VALUBusy was 27%).
__global__ __launch_bounds__(512, 1)
void gemm_qkv_kernel(const unsigned short* __restrict__ A,
                     const unsigned short* __restrict__ Bw,
                     unsigned short* __restrict__ q_r,
                     unsigned short* __restrict__ k_r,
                     unsigned short* __restrict__ vc,
                     const float* __restrict__ cosT,
                     const float* __restrict__ sinT,
                     int M, int N, int K) {
  __shared__ __align__(16) unsigned short lA[3][128 * 64];   // 3 x 16KB
  __shared__ __align__(16) unsigned short lB[3][256 * 64];   // 3 x 32KB
  const int tid  = threadIdx.x;
  const int wave = tid >> 6, lane = tid & 63;
  const int wm = wave >> 2, wn = wave & 3;       // 2M x 4N wave grid
  const int lg = lane >> 4, ll = lane & 15;

  // L2-aware XCD map (r11): grid 24(n) x 32(m)
  const int nbx = gridDim.x;
  const int id  = blockIdx.y * nbx + blockIdx.x;
  const int k8 = id & 7, q8 = id >> 3;
  const int ng = q8 >> 5, r8 = q8 & 31;
  const int m_tile = (k8 >> 1) * 8 + (r8 & 7);
  const int n_tile = (k8 & 1) * 12 + ng * 4 + (r8 >> 3);
  const int m0 = m_tile * 128, n0 = n_tile * 256;

  f32x4 acc[4][4];
#pragma unroll
  for (int i = 0; i < 4; ++i)
#pragma unroll
    for (int j = 0; j < 4; ++j) acc[i][j] = (f32x4){0.f, 0.f, 0.f, 0.f};

  const unsigned short* aP[2];
  const unsigned short* bP[4];
  int aD[2], bD[4];
#pragma unroll
  for (int i = 0; i < 2; ++i) {
    int cb = (i * 8 + wave) * 64 + lane;
    int cs = cb ^ ((cb >> 3) & 7);
    aP[i] = A + (size_t)(m0 + (cs >> 3)) * K + (cs & 7) * 8;
    aD[i] = cb * 8;
  }
#pragma unroll
  for (int i = 0; i < 4; ++i) {
    int cb = (i * 8 + wave) * 64 + lane;
    int cs = cb ^ ((cb >> 3) & 7);
    bP[i] = Bw + (size_t)(n0 + (cs >> 3)) * K + (cs & 7) * 8;
    bD[i] = cb * 8;
  }

  auto STAGE = [&](int buf, int t) {
    const int kt = t << 6;
#pragma unroll
    for (int i = 0; i < 2; ++i) gload_lds16(aP[i] + kt, &lA[buf][aD[i]]);
#pragma unroll
    for (int i = 0; i < 4; ++i) gload_lds16(bP[i] + kt, &lB[buf][bD[i]]);
  };

  // hoisted per-lane fragment bases (byte offsets)
  const int xo = (ll & 7) << 4;
  const int laneA0 = wm * 8192 + ((ll * 128 + lg * 16) ^ xo);
  const int laneA1 = wm * 8192 + ((ll * 128 + 64 + lg * 16) ^ xo);
  const int laneB0 = wn * 8192 + ((ll * 128 + lg * 16) ^ xo);
  const int laneB1 = wn * 8192 + ((ll * 128 + 64 + lg * 16) ^ xo);

  const int NT = K >> 6;
  STAGE(0, 0);
  STAGE(1, 1);
  asm volatile("s_waitcnt vmcnt(6)" ::: "memory");
  asm volatile("s_barrier" ::: "memory");

  for (int t = 0; t < NT; ++t) {
    const int cur = t % 3;
    const char* pA0 = (const char*)&lA[cur][0] + laneA0;
    const char* pA1 = (const char*)&lA[cur][0] + laneA1;
    const char* pB0 = (const char*)&lB[cur][0] + laneB0;
    const char* pB1 = (const char*)&lB[cur][0] + laneB1;

    bf16x8 af[4][2], bfr[2][2][2];
#pragma unroll
    for (int fq = 0; fq < 4; ++fq) {
      af[fq][0] = load8((const unsigned short*)(pA0 + fq * 2048));
      af[fq][1] = load8((const unsigned short*)(pA1 + fq * 2048));
    }
#pragma unroll
    for (int nh = 0; nh < 2; ++nh)
#pragma unroll
      for (int fq = 0; fq < 2; ++fq) {
        bfr[nh][fq][0] = load8((const unsigned short*)(pB0 + nh * 4096 + fq * 2048));
        bfr[nh][fq][1] = load8((const unsigned short*)(pB1 + nh * 4096 + fq * 2048));
      }

    if (t + 2 < NT) STAGE((t + 2) % 3, t + 2);

    __builtin_amdgcn_s_setprio(1);
#pragma unroll
    for (int nh = 0; nh < 2; ++nh)
#pragma unroll
      for (int fq = 0; fq < 4; ++fq)
#pragma unroll
        for (int gq = 0; gq < 2; ++gq)
#pragma unroll
          for (int kk = 0; kk < 2; ++kk)
            acc[fq][nh * 2 + gq] =
                mfma_bf16(af[fq][kk], bfr[nh][gq][kk], acc[fq][nh * 2 + gq]);
    __builtin_amdgcn_s_setprio(0);

    if (t + 2 < NT)
      asm volatile("s_waitcnt vmcnt(6)" ::: "memory");
    else if (t + 1 < NT)
      asm volatile("s_waitcnt vmcnt(0)" ::: "memory");
    asm volatile("s_barrier" ::: "memory");
  }

  // ---- fused RoPE epilogue (after final barrier: LDS reuse is safe) ----
  const int g   = n_tile * 4 + wn;
  const int sub = g % 6, hh = g / 6;
  float* slot = (wave < 3) ? (float*)&lA[wave][0]
                           : (float*)&lB[0][0] + (size_t)(wave - 3) * 4096;
  const float* pslot = ((wave ^ 1) < 3)
                           ? (const float*)&lA[wave ^ 1][0]
                           : (const float*)&lB[0][0] + (size_t)((wave ^ 1) - 3) * 4096;
#pragma unroll
  for (int fm = 0; fm < 4; ++fm)
#pragma unroll
    for (int fn = 0; fn < 4; ++fn)
#pragma unroll
      for (int j = 0; j < 4; ++j)
        slot[(fm * 16 + fn * 4 + j) * 64 + lane] = acc[fm][fn][j];
  __syncthreads();

  if (sub < 4) {
    const bool hi = (sub & 1);
    unsigned short* dst = (sub < 2) ? q_r : k_r;
    const int dbase = hi ? 64 : 0;
#pragma unroll
    for (int fm = 0; fm < 4; ++fm)
#pragma unroll
      for (int fn = 0; fn < 4; ++fn)
#pragma unroll
        for (int j = 0; j < 4; ++j) {
          int r  = m0 + wm * 64 + fm * 16 + lg * 4 + j;
          int s  = r & (S_DIM - 1), bb = r >> 11;
          int dp = fn * 16 + ll;
          float c  = cosT[(s << 6) + dp];
          float sn = sinT[(s << 6) + dp];
          float a  = acc[fm][fn][j];
          float pv = pslot[(fm * 16 + fn * 4 + j) * 64 + lane];
          float ov = hi ? fmaf(a, c, pv * sn) : fmaf(a, c, -pv * sn);
          size_t ob = ((size_t)(bb * NHEAD + hh) * S_DIM + s) * HD_DIM
                      + dbase + dp;
          dst[ob] = f2bf(ov);
        }
  } else {
    const int dbase = (sub - 4) * 64;
#pragma unroll
    for (int fm = 0; fm < 4; ++fm)
#pragma unroll
      for (int fn = 0; fn < 4; ++fn)
#pragma unroll
        for (int j = 0; j < 4; ++j) {
          int r  = m0 + wm * 64 + fm * 16 + lg * 4 + j;
          int dp = fn * 16 + ll;
          vc[(size_t)r * H_DIM + hh * HD_DIM + dbase + dp] =
              f2bf(acc[fm][fn][j]);
        }
  }
}

// ------------------------------------------------- triple-buffered GEMM (B^T)
// Kept for the output projection (256 blocks = exactly 1 round there).
template <bool OUT_BF16, bool QKV_MAP>
__global__ __launch_bounds__(512, 1)
void gemm3b_kernel(const unsigned short* __restrict__ A,
                   const unsigned short* __restrict__ Bw,
                   void* __restrict__ C, int M, int N, int K) {
  __shared__ __align__(16) unsigned short lA[3][128 * 64];   // 3 x 16KB
  __shared__ __align__(16) unsigned short lB[3][256 * 64];   // 3 x 32KB
  const int tid  = threadIdx.x;
  const int wave = tid >> 6, lane = tid & 63;
  const int wm = wave >> 2, wn = wave & 3;       // 2M x 4N wave grid
  const int lg = lane >> 4, ll = lane & 15;

  const int nbx = gridDim.x;
  const int id  = blockIdx.y * nbx + blockIdx.x;
  int m_tile, n_tile;
  if (QKV_MAP) {
    const int k = id & 7, q = id >> 3;
    const int ng = q >> 5, r = q & 31;
    m_tile = (k >> 1) * 8 + (r & 7);
    n_tile = (k & 1) * 12 + ng * 4 + (r >> 3);
  } else {
    const int nwg = gridDim.x * gridDim.y;
    const int swz = (id & 7) * (nwg >> 3) + (id >> 3);
    m_tile = swz / nbx;
    n_tile = swz % nbx;
  }
  const int m0 = m_tile * 128, n0 = n_tile * 256;

  f32x4 acc[4][4];
#pragma unroll
  for (int i = 0; i < 4; ++i)
#pragma unroll
    for (int j = 0; j < 4; ++j) acc[i][j] = (f32x4){0.f, 0.f, 0.f, 0.f};

  const unsigned short* aP[2];
  const unsigned short* bP[4];
  int aD[2], bD[4];
#pragma unroll
  for (int i = 0; i < 2; ++i) {
    int cb = (i * 8 + wave) * 64 + lane;
    int cs = cb ^ ((cb >> 3) & 7);
    aP[i] = A + (size_t)(m0 + (cs >> 3)) * K + (cs & 7) * 8;
    aD[i] = cb * 8;
  }
#pragma unroll
  for (int i = 0; i < 4; ++i) {
    int cb = (i * 8 + wave) * 64 + lane;
    int cs = cb ^ ((cb >> 3) & 7);
    bP[i] = Bw + (size_t)(n0 + (cs >> 3)) * K + (cs & 7) * 8;
    bD[i] = cb * 8;
  }

  auto STAGE = [&](int buf, int t) {
    const int kt = t << 6;
#pragma unroll
    for (int i = 0; i < 2; ++i) gload_lds16(aP[i] + kt, &lA[buf][aD[i]]);
#pragma unroll
    for (int i = 0; i < 4; ++i) gload_lds16(bP[i] + kt, &lB[buf][bD[i]]);
  };

  const int xo = (ll & 7) << 4;
  const int laneA0 = wm * 8192 + ((ll * 128 + lg * 16) ^ xo);
  const int laneA1 = wm * 8192 + ((ll * 128 + 64 + lg * 16) ^ xo);
  const int laneB0 = wn * 8192 + ((ll * 128 + lg * 16) ^ xo);
  const int laneB1 = wn * 8192 + ((ll * 128 + 64 + lg * 16) ^ xo);

  const int NT = K >> 6;
  STAGE(0, 0);
  if (NT > 1) {
    STAGE(1, 1);
    asm volatile("s_waitcnt vmcnt(6)" ::: "memory");
  } else {
    asm volatile("s_waitcnt vmcnt(0)" ::: "memory");
  }
  asm volatile("s_barrier" ::: "memory");

  for (int t = 0; t < NT; ++t) {
    const int cur = t % 3;
    const char* pA0 = (const char*)&lA[cur][0] + laneA0;
    const char* pA1 = (const char*)&lA[cur][0] + laneA1;
    const char* pB0 = (const char*)&lB[cur][0] + laneB0;
    const char* pB1 = (const char*)&lB[cur][0] + laneB1;

    bf16x8 af[4][2], bfr[2][2][2];
#pragma unroll
    for (int fq = 0; fq < 4; ++fq) {
      af[fq][0] = load8((const unsigned short*)(pA0 + fq * 2048));
      af[fq][1] = load8((const unsigned short*)(pA1 + fq * 2048));
    }
#pragma unroll
    for (int nh = 0; nh < 2; ++nh)
#pragma unroll
      for (int fq = 0; fq < 2; ++fq) {
        bfr[nh][fq][0] = load8((const unsigned short*)(pB0 + nh * 4096 + fq * 2048));
        bfr[nh][fq][1] = load8((const unsigned short*)(pB1 + nh * 4096 + fq * 2048));
      }

    if (t + 2 < NT) STAGE((t + 2) % 3, t + 2);

    __builtin_amdgcn_s_setprio(1);
#pragma unroll
    for (int nh = 0; nh < 2; ++nh)
#pragma unroll
      for (int fq = 0; fq < 4; ++fq)
#pragma unroll
        for (int gq = 0; gq < 2; ++gq)
#pragma unroll
          for (int kk = 0; kk < 2; ++kk)
            acc[fq][nh * 2 + gq] =
                mfma_bf16(af[fq][kk], bfr[nh][gq][kk], acc[fq][nh * 2 + gq]);
    __builtin_amdgcn_s_setprio(0);

    if (t + 2 < NT)
      asm volatile("s_waitcnt vmcnt(6)" ::: "memory");
    else if (t + 1 < NT)
      asm volatile("s_waitcnt vmcnt(0)" ::: "memory");
    asm volatile("s_barrier" ::: "memory");
  }

#pragma unroll
  for (int fm = 0; fm < 4; ++fm)
#pragma unroll
    for (int fn = 0; fn < 4; ++fn)
#pragma unroll
      for (int j = 0; j < 4; ++j) {
        int r   = m0 + wm * 64 + fm * 16 + lg * 4 + j;
        int col = n0 + wn * 64 + fn * 16 + ll;
        if (OUT_BF16)
          ((unsigned short*)C)[(size_t)r * N + col] = f2bf(acc[fm][fn][j]);
        else
          ((float*)C)[(size_t)r * N + col] = acc[fm][fn][j];
      }
}

// ---------------------------------------------------------------- V transpose
// v_t[bh][d][s] <- vc[b*S+s][h*128+d] (compact layout); 64x64 tiles via LDS.
__global__ __launch_bounds__(256)
void vtrans_kernel(const unsigned short* __restrict__ vc,
                   unsigned short* __restrict__ vt) {
  __shared__ unsigned short t[64 * 65];
  int st = blockIdx.x, dt = blockIdx.y, bh = blockIdx.z;
  int b = bh >> 4, h = bh & 15;
  int s0 = st * 64, d0 = dt * 64;
  int tid = threadIdx.x;
#pragma unroll
  for (int it = 0; it < 2; ++it) {
    int c = it * 256 + tid;                 // 0..511
    int sl = c >> 3, dc = c & 7;
    const unsigned short* src =
        vc + (size_t)(b * S_DIM + s0 + sl) * H_DIM + h * HD_DIM + d0 + dc * 8;
    s16x8 v = *(const s16x8*)src;
#pragma unroll
    for (int i = 0; i < 8; ++i) t[(dc * 8 + i) * 65 + sl] = (unsigned short)v[i];
  }
  __syncthreads();
#pragma unroll
  for (int it = 0; it < 2; ++it) {
    int c = it * 256 + tid;
    int dl = c >> 3, sc = c & 7;
    s16x8 v;
#pragma unroll
    for (int i = 0; i < 8; ++i) v[i] = (short)t[dl * 65 + sc * 8 + i];
    *(s16x8*)(vt + ((size_t)bh * HD_DIM + d0 + dl) * S_DIM + s0 + sc * 8) = v;
  }
}

// ---------------------------------------------------------------- attention
// 8-wave, KVBLK=128 staging (r22): grid (p=8, bh=32), 512 threads,
// 128 q-rows/block; pairing {p, 15-p} -> 17 kv128-tiles every block.
// Fragment addressing hoisted (same bit-disjointness argument as GEMM).
__global__ __launch_bounds__(512, 1)
void attn_kernel(const unsigned short* __restrict__ qr,
                 const unsigned short* __restrict__ kr,
                 const unsigned short* __restrict__ vt,
                 unsigned short* __restrict__ out) {
  __shared__ __align__(16) unsigned short kbuf[2][128 * 128]; // 2 x 32KB
  __shared__ __align__(16) unsigned short vbuf[2][128 * 128]; // 2 x 32KB
  __shared__ __align__(16) unsigned short plds[8][16 * 72];   // 18KB
  const int p = blockIdx.x, bh = blockIdx.y;
  const int wave = threadIdx.x >> 6, lane = threadIdx.x & 63;
  const int b = bh >> 4, h = bh & 15;
  const int lg = lane >> 4, ll = lane & 15;
  const unsigned short* Qb = qr + (size_t)bh * S_DIM * HD_DIM;
  const unsigned short* Kb = kr + (size_t)bh * S_DIM * HD_DIM;
  const unsigned short* Vb = vt + (size_t)bh * HD_DIM * S_DIM;
  const float kE  = 0.12752792f;   // (1/sqrt(128)) * log2(e)
  const float THR = 11.5416f;      // 8 * log2(e)  (T13 threshold, k-domain)
  unsigned short* pw = &plds[wave][0];

  // hoisted per-lane fragment bases (byte offsets)
  const int xo = (ll & 7) << 4;
  int laneK[4], laneV[2];
#pragma unroll
  for (int kk = 0; kk < 4; ++kk)
    laneK[kk] = (ll * 256 + kk * 64 + lg * 16) ^ xo;
#pragma unroll
  for (int c = 0; c < 2; ++c)
    laneV[c] = (ll * 256 + c * 64 + lg * 16) ^ xo;

  for (int seg = 0; seg < 2; ++seg) {
    const int qt = seg ? (15 - p) : p;         // 128-row q-tile index
    const int qbase = qt * 128 + wave * 16;
    const int ntb = qt + 1;                    // kv128-tile count
    const int ntb64 = 2 * qt + 2;              // kv64-half count

    auto STAGE = [&](int buf, int t) {
      const int k0 = t * 128;
#pragma unroll
      for (int i = 0; i < 4; ++i) {
        int cb = (i * 8 + wave) * 64 + lane;   // 0..2047
        int cs = cb ^ ((cb >> 4) & 7);
        gload_lds16(Kb + (size_t)(k0 + (cs >> 4)) * HD_DIM + (cs & 15) * 8,
                    &kbuf[buf][cb * 8]);
      }
#pragma unroll
      for (int i = 0; i < 4; ++i) {
        int cb = (i * 8 + wave) * 64 + lane;
        int cs = cb ^ ((cb >> 4) & 7);
        gload_lds16(Vb + (size_t)(cs >> 4) * S_DIM + k0 + (cs & 15) * 8,
                    &vbuf[buf][cb * 8]);
      }
    };

    bf16x8 aq[4];
#pragma unroll
    for (int kk = 0; kk < 4; ++kk)
      aq[kk] = load8(Qb + (size_t)(qbase + ll) * HD_DIM + kk * 32 + lg * 8);

    float mk[4], lsum[4];
    f32x4 o[8];
#pragma unroll
    for (int j = 0; j < 4; ++j) { mk[j] = -1e30f; lsum[j] = 0.f; }
#pragma unroll
    for (int f = 0; f < 8; ++f) o[f] = (f32x4){0.f, 0.f, 0.f, 0.f};

    STAGE(0, 0);
    __syncthreads();   // implicit vmcnt(0) drain

    for (int t = 0; t < ntb; ++t) {
      const int cur = t & 1;
      if (t + 1 < ntb) STAGE(cur ^ 1, t + 1);  // full-tile latency cover
      const char* kb = (const char*)&kbuf[cur][0];
      const char* vb = (const char*)&vbuf[cur][0];

#pragma unroll
      for (int half = 0; half < 2; ++half) {
        const int th = 2 * t + half;           // kv64-half index
        const int k0h = th * 64;
        const bool maskt = (th >= ntb64 - 2);  // block-uniform

        f32x4 s[4];
#pragma unroll
        for (int kf = 0; kf < 4; ++kf) s[kf] = (f32x4){0.f, 0.f, 0.f, 0.f};
        __builtin_amdgcn_s_setprio(1);
#pragma unroll
        for (int kf = 0; kf < 4; ++kf)
#pragma unroll
          for (int kk = 0; kk < 4; ++kk)
            s[kf] = mfma_bf16(
                aq[kk],
                load8((const unsigned short*)(kb + laneK[kk] + half * 16384 +
                                              kf * 4096)),
                s[kf]);
        __builtin_amdgcn_s_setprio(0);

        if (maskt) {
#pragma unroll
          for (int kf = 0; kf < 4; ++kf) {
            int kcol = k0h + kf * 16 + ll;
#pragma unroll
            for (int j = 0; j < 4; ++j) {
              int qrow = qbase + lg * 4 + j;
              if (kcol > qrow) s[kf][j] = -1e31f;
            }
          }
        }

        float pmax[4];
        bool ok = true;
#pragma unroll
        for (int j = 0; j < 4; ++j) {
          pmax[j] = fmaxf(fmaxf(s[0][j], s[1][j]), fmaxf(s[2][j], s[3][j]));
          ok = ok && (pmax[j] * kE - mk[j] <= THR);
        }
        if (!__all(ok)) {                      // rare: ~once per segment
#pragma unroll
          for (int j = 0; j < 4; ++j) {
            float rm = pmax[j] * kE;
#pragma unroll
            for (int off = 1; off < 16; off <<= 1)
              rm = fmaxf(rm, __shfl_xor(rm, off, 64));
            rm = fmaxf(rm, mk[j]);
            float corr = exp2f(mk[j] - rm);
            mk[j] = rm;
            lsum[j] *= corr;
#pragma unroll
            for (int f = 0; f < 8; ++f) o[f][j] *= corr;
          }
        }
#pragma unroll
        for (int j = 0; j < 4; ++j) {
          int prow = (lg * 4 + j) * 72;
#pragma unroll
          for (int kf = 0; kf < 4; ++kf) {
            float e = exp2f(fmaf(s[kf][j], kE, -mk[j]));
            lsum[j] += e;
            pw[prow + kf * 16 + ll] = f2bf(e);
          }
        }

        bf16x8 pa0 = load8(&pw[ll * 72 + lg * 8]);
        bf16x8 pa1 = load8(&pw[ll * 72 + 32 + lg * 8]);
        __builtin_amdgcn_s_setprio(1);
#pragma unroll
        for (int f = 0; f < 8; ++f) {
          o[f] = mfma_bf16(
              pa0,
              load8((const unsigned short*)(vb + laneV[0] + f * 4096 +
                                            half * 128)),
              o[f]);
          o[f] = mfma_bf16(
              pa1,
              load8((const unsigned short*)(vb + laneV[1] + f * 4096 +
                                            half * 128)),
              o[f]);
        }
        __builtin_amdgcn_s_setprio(0);
      }

      __syncthreads();   // once per 128-tile: drains staged vmcnt + dbuf guard
    }

#pragma unroll
    for (int j = 0; j < 4; ++j) {
      float l = lsum[j];
#pragma unroll
      for (int off = 1; off < 16; off <<= 1) l += __shfl_xor(l, off, 64);
      lsum[j] = 1.0f / l;
    }
#pragma unroll
    for (int f = 0; f < 8; ++f)
#pragma unroll
      for (int j = 0; j < 4; ++j) {
        int srow = qbase + lg * 4 + j;
        out[((size_t)(b * S_DIM + srow)) * H_DIM + h * HD_DIM + f * 16 + ll] =
            f2bf(o[f][j] * lsum[j]);
      }
  }
}

// ---------------------------------------------------------------- launch
extern "C" void kernel_launch(void* const* d_in, const int* in_sizes, int n_in,
                              void* d_out, int out_size, void* d_ws, size_t ws_size,
                              hipStream_t stream) {
  (void)in_sizes; (void)n_in; (void)out_size; (void)ws_size;
  const float* hidden = (const float*)d_in[0];
  const float* wqkv   = (const float*)d_in[1];
  const float* wo     = (const float*)d_in[2];
  char* ws = (char*)d_ws;
  unsigned short* hid_b  = (unsigned short*)(ws);               // 16,777,216
  unsigned short* wqkv_b = (unsigned short*)(ws + 16777216);    // 25,165,824
  unsigned short* wo_b   = (unsigned short*)(ws + 41943040);    //  8,388,608
  unsigned short* vc     = (unsigned short*)(ws + 50331648);    // 16,777,216 (compact V)
  unsigned short* q_r    = (unsigned short*)(ws + 100663296);   // 16,777,216
  unsigned short* k_r    = (unsigned short*)(ws + 117440512);   // 16,777,216
  unsigned short* v_t    = (unsigned short*)(ws + 134217728);   // 16,777,216
  unsigned short* attn   = (unsigned short*)(ws + 150994944);   // 16,777,216
  float* cosT            = (float*)(ws + 167772160);            //    524,288
  float* sinT            = (float*)(ws + 168296448);            //    524,288

  prep_kernel<<<2048, 256, 0, stream>>>(hidden, wqkv, wo, hid_b, wqkv_b, wo_b,
                                        cosT, sinT);

  // QKV projection + fused RoPE epilogue: grid 24x32 = 768 = 3 rounds
  gemm_qkv_kernel<<<dim3(O3 / 256, BS / 128), 512, 0, stream>>>(
      hid_b, wqkv_b, q_r, k_r, vc, cosT, sinT, BS, O3, H_DIM);

  vtrans_kernel<<<dim3(32, 2, 32), 256, 0, stream>>>(vc, v_t);

  // attention: 8-wave blocks, KVBLK=128 staging, grid 8x32 = 256 = 1/CU
  attn_kernel<<<dim3(8, 32), 512, 0, stream>>>(q_r, k_r, v_t, attn);

  // output projection: grid 8x32 = 256 = exactly 1 round; chunked map
  gemm3b_kernel<false, false><<<dim3(H_DIM / 256, BS / 128), 512, 0, stream>>>(
      attn, wo_b, d_out, BS, H_DIM, H_DIM);
}

// Round 25
// 237.786 us; speedup vs baseline: 1.1943x; 1.0363x over previous
//
#include <hip/hip_runtime.h>
#include <hip/hip_bf16.h>
#include <cstdint>
#include <cstddef>

// Problem constants
#define S_DIM 2048
#define H_DIM 2048
#define NHEAD 16
#define HD_DIM 128
#define O3    6144   // 3*H
#define BS    4096   // B*S
#define NBH   32     // B*NHEAD

typedef short  s16x4  __attribute__((ext_vector_type(4)));
typedef short  s16x8  __attribute__((ext_vector_type(8)));
typedef __bf16 bf16x8 __attribute__((ext_vector_type(8)));
typedef float  f32x4  __attribute__((ext_vector_type(4)));

__device__ __forceinline__ unsigned short f2bf(float f) {
  unsigned int b = __float_as_uint(f);
  b += 0x7FFFu + ((b >> 16) & 1u);          // round-to-nearest-even
  return (unsigned short)(b >> 16);
}
__device__ __forceinline__ float bf2f(unsigned short u) {
  return __uint_as_float(((unsigned int)u) << 16);
}
__device__ __forceinline__ bf16x8 load8(const unsigned short* p) {
  s16x8 r = *(const s16x8*)p;
  return __builtin_bit_cast(bf16x8, r);
}
__device__ __forceinline__ f32x4 mfma_bf16(bf16x8 a, bf16x8 b, f32x4 c) {
  return __builtin_amdgcn_mfma_f32_16x16x32_bf16(a, b, c, 0, 0, 0);
}
__device__ __forceinline__ void gload_lds16(const void* g, void* l) {
  __builtin_amdgcn_global_load_lds(
      (__attribute__((address_space(1))) unsigned int*)g,
      (__attribute__((address_space(3))) unsigned int*)l, 16, 0, 0);
}

// -------------------------------------------------- fused prep (one launch)
__global__ void prep_kernel(const float* __restrict__ hid,
                            const float* __restrict__ wqkv,
                            const float* __restrict__ wo,
                            unsigned short* __restrict__ hid_b,
                            unsigned short* __restrict__ wqkv_b,
                            unsigned short* __restrict__ wo_b,
                            float* __restrict__ cosT,
                            float* __restrict__ sinT) {
  const int nA = 2097152, nB = 3145728, nC = 1048576, nD = 131072;
  const int total = nA + nB + nC + nD;
  int stride = gridDim.x * blockDim.x;
  for (int i = blockIdx.x * blockDim.x + threadIdx.x; i < total; i += stride) {
    if (i < nA + nB + nC) {
      const float* src; unsigned short* dst; int j;
      if (i < nA)            { src = hid;  dst = hid_b;  j = i; }
      else if (i < nA + nB)  { src = wqkv; dst = wqkv_b; j = i - nA; }
      else                   { src = wo;   dst = wo_b;   j = i - nA - nB; }
      float4 v = ((const float4*)src)[j];
      ushort4 o;
      o.x = f2bf(v.x); o.y = f2bf(v.y); o.z = f2bf(v.z); o.w = f2bf(v.w);
      ((ushort4*)dst)[j] = o;
    } else {
      int idx = i - nA - nB - nC;          // 0..131071 = s*64 + d
      int s = idx >> 6, d = idx & 63;
      float inv = expf(-((float)d / 64.0f) * 9.210340371976184f);
      float ang = (float)s * inv;
      float sn, cs;
      sincosf(ang, &sn, &cs);
      cosT[idx] = cs;
      sinT[idx] = sn;
    }
  }
}

// ------------------------------------- QKV GEMM with fused RoPE + V-transpose
// Mainloop = proven gemm3b (hoisted fragment addressing, r24). Epilogue:
// q/k waves exchange halves via LDS (pair = wave^1) and apply RoPE; v waves
// write their slot in TRANSPOSE layout [d][m ^ ((d&7)<<3)] and store
// v_t[bh][d][s] rows directly -> the separate vtrans kernel (67MB round
// trip) is eliminated. v pairs with v (sub 4<->5 under wave^1), so the
// layout fork never touches the q/k exchange slots.
__global__ __launch_bounds__(512, 1)
void gemm_qkv_kernel(const unsigned short* __restrict__ A,
                     const unsigned short* __restrict__ Bw,
                     unsigned short* __restrict__ q_r,
                     unsigned short* __restrict__ k_r,
                     unsigned short* __restrict__ v_t,
                     const float* __restrict__ cosT,
                     const float* __restrict__ sinT,
                     int M, int N, int K) {
  __shared__ __align__(16) unsigned short lA[3][128 * 64];   // 3 x 16KB
  __shared__ __align__(16) unsigned short lB[3][256 * 64];   // 3 x 32KB
  const int tid  = threadIdx.x;
  const int wave = tid >> 6, lane = tid & 63;
  const int wm = wave >> 2, wn = wave & 3;       // 2M x 4N wave grid
  const int lg = lane >> 4, ll = lane & 15;

  // L2-aware XCD map (r11): grid 24(n) x 32(m)
  const int nbx = gridDim.x;
  const int id  = blockIdx.y * nbx + blockIdx.x;
  const int k8 = id & 7, q8 = id >> 3;
  const int ng = q8 >> 5, r8 = q8 & 31;
  const int m_tile = (k8 >> 1) * 8 + (r8 & 7);
  const int n_tile = (k8 & 1) * 12 + ng * 4 + (r8 >> 3);
  const int m0 = m_tile * 128, n0 = n_tile * 256;

  f32x4 acc[4][4];
#pragma unroll
  for (int i = 0; i < 4; ++i)
#pragma unroll
    for (int j = 0; j < 4; ++j) acc[i][j] = (f32x4){0.f, 0.f, 0.f, 0.f};

  const unsigned short* aP[2];
  const unsigned short* bP[4];
  int aD[2], bD[4];
#pragma unroll
  for (int i = 0; i < 2; ++i) {
    int cb = (i * 8 + wave) * 64 + lane;
    int cs = cb ^ ((cb >> 3) & 7);
    aP[i] = A + (size_t)(m0 + (cs >> 3)) * K + (cs & 7) * 8;
    aD[i] = cb * 8;
  }
#pragma unroll
  for (int i = 0; i < 4; ++i) {
    int cb = (i * 8 + wave) * 64 + lane;
    int cs = cb ^ ((cb >> 3) & 7);
    bP[i] = Bw + (size_t)(n0 + (cs >> 3)) * K + (cs & 7) * 8;
    bD[i] = cb * 8;
  }

  auto STAGE = [&](int buf, int t) {
    const int kt = t << 6;
#pragma unroll
    for (int i = 0; i < 2; ++i) gload_lds16(aP[i] + kt, &lA[buf][aD[i]]);
#pragma unroll
    for (int i = 0; i < 4; ++i) gload_lds16(bP[i] + kt, &lB[buf][bD[i]]);
  };

  // hoisted per-lane fragment bases (byte offsets)
  const int xo = (ll & 7) << 4;
  const int laneA0 = wm * 8192 + ((ll * 128 + lg * 16) ^ xo);
  const int laneA1 = wm * 8192 + ((ll * 128 + 64 + lg * 16) ^ xo);
  const int laneB0 = wn * 8192 + ((ll * 128 + lg * 16) ^ xo);
  const int laneB1 = wn * 8192 + ((ll * 128 + 64 + lg * 16) ^ xo);

  const int NT = K >> 6;
  STAGE(0, 0);
  STAGE(1, 1);
  asm volatile("s_waitcnt vmcnt(6)" ::: "memory");
  asm volatile("s_barrier" ::: "memory");

  for (int t = 0; t < NT; ++t) {
    const int cur = t % 3;
    const char* pA0 = (const char*)&lA[cur][0] + laneA0;
    const char* pA1 = (const char*)&lA[cur][0] + laneA1;
    const char* pB0 = (const char*)&lB[cur][0] + laneB0;
    const char* pB1 = (const char*)&lB[cur][0] + laneB1;

    bf16x8 af[4][2], bfr[2][2][2];
#pragma unroll
    for (int fq = 0; fq < 4; ++fq) {
      af[fq][0] = load8((const unsigned short*)(pA0 + fq * 2048));
      af[fq][1] = load8((const unsigned short*)(pA1 + fq * 2048));
    }
#pragma unroll
    for (int nh = 0; nh < 2; ++nh)
#pragma unroll
      for (int fq = 0; fq < 2; ++fq) {
        bfr[nh][fq][0] = load8((const unsigned short*)(pB0 + nh * 4096 + fq * 2048));
        bfr[nh][fq][1] = load8((const unsigned short*)(pB1 + nh * 4096 + fq * 2048));
      }

    if (t + 2 < NT) STAGE((t + 2) % 3, t + 2);

    __builtin_amdgcn_s_setprio(1);
#pragma unroll
    for (int nh = 0; nh < 2; ++nh)
#pragma unroll
      for (int fq = 0; fq < 4; ++fq)
#pragma unroll
        for (int gq = 0; gq < 2; ++gq)
#pragma unroll
          for (int kk = 0; kk < 2; ++kk)
            acc[fq][nh * 2 + gq] =
                mfma_bf16(af[fq][kk], bfr[nh][gq][kk], acc[fq][nh * 2 + gq]);
    __builtin_amdgcn_s_setprio(0);

    if (t + 2 < NT)
      asm volatile("s_waitcnt vmcnt(6)" ::: "memory");
    else if (t + 1 < NT)
      asm volatile("s_waitcnt vmcnt(0)" ::: "memory");
    asm volatile("s_barrier" ::: "memory");
  }

  // ---- fused epilogue (after final barrier: LDS reuse is safe) ----
  const int g   = n_tile * 4 + wn;
  const int sub = g % 6, hh = g / 6;
  float* slot = (wave < 3) ? (float*)&lA[wave][0]
                           : (float*)&lB[0][0] + (size_t)(wave - 3) * 4096;
  const float* pslot = ((wave ^ 1) < 3)
                           ? (const float*)&lA[wave ^ 1][0]
                           : (const float*)&lB[0][0] + (size_t)((wave ^ 1) - 3) * 4096;

  if (sub < 4) {
    // exchange layout [idx][lane] (conflict-free)
#pragma unroll
    for (int fm = 0; fm < 4; ++fm)
#pragma unroll
      for (int fn = 0; fn < 4; ++fn)
#pragma unroll
        for (int j = 0; j < 4; ++j)
          slot[(fm * 16 + fn * 4 + j) * 64 + lane] = acc[fm][fn][j];
  } else {
    // transpose layout [d][m ^ ((d&7)<<3)] (bijective per row)
#pragma unroll
    for (int fm = 0; fm < 4; ++fm)
#pragma unroll
      for (int fn = 0; fn < 4; ++fn)
#pragma unroll
        for (int j = 0; j < 4; ++j) {
          int d = fn * 16 + ll;
          int m = fm * 16 + lg * 4 + j;
          slot[d * 64 + (m ^ ((d & 7) << 3))] = acc[fm][fn][j];
        }
  }
  __syncthreads();

  if (sub < 4) {
    // q/k with RoPE: lo (sub even): out = a*c - p*s ; hi: out = a*c + p*s
    const bool hi = (sub & 1);
    unsigned short* dst = (sub < 2) ? q_r : k_r;
    const int dbase = hi ? 64 : 0;
#pragma unroll
    for (int fm = 0; fm < 4; ++fm)
#pragma unroll
      for (int fn = 0; fn < 4; ++fn)
#pragma unroll
        for (int j = 0; j < 4; ++j) {
          int r  = m0 + wm * 64 + fm * 16 + lg * 4 + j;
          int s  = r & (S_DIM - 1), bb = r >> 11;
          int dp = fn * 16 + ll;
          float c  = cosT[(s << 6) + dp];
          float sn = sinT[(s << 6) + dp];
          float a  = acc[fm][fn][j];
          float pv = pslot[(fm * 16 + fn * 4 + j) * 64 + lane];
          float ov = hi ? fmaf(a, c, pv * sn) : fmaf(a, c, -pv * sn);
          size_t ob = ((size_t)(bb * NHEAD + hh) * S_DIM + s) * HD_DIM
                      + dbase + dp;
          dst[ob] = f2bf(ov);
        }
  } else {
    // v: read back transposed, store v_t[bh][d][s] rows (16B per lane/iter)
    const int dbase = (sub - 4) * 64;
    const int bb = m0 >> 11;                       // block fully in one batch
    const int s0g = (m0 & (S_DIM - 1)) + wm * 64;
    unsigned short* vrow =
        v_t + ((size_t)(bb * NHEAD + hh) * HD_DIM + dbase) * S_DIM;
#pragma unroll
    for (int it = 0; it < 8; ++it) {
      int d = it * 8 + (lane >> 3);
      int c = lane & 7;
      int mb = (c ^ (d & 7)) * 8;                  // stored m-block
      const float* sp = slot + d * 64 + c * 8;     // 8 contiguous floats
      s16x8 ov;
#pragma unroll
      for (int e = 0; e < 8; ++e) ov[e] = (short)f2bf(sp[e]);
      *(s16x8*)(vrow + (size_t)d * S_DIM + s0g + mb) = ov;
    }
  }
}

// ------------------------------------------------- triple-buffered GEMM (B^T)
// Kept for the output projection (256 blocks = exactly 1 round there).
template <bool OUT_BF16, bool QKV_MAP>
__global__ __launch_bounds__(512, 1)
void gemm3b_kernel(const unsigned short* __restrict__ A,
                   const unsigned short* __restrict__ Bw,
                   void* __restrict__ C, int M, int N, int K) {
  __shared__ __align__(16) unsigned short lA[3][128 * 64];   // 3 x 16KB
  __shared__ __align__(16) unsigned short lB[3][256 * 64];   // 3 x 32KB
  const int tid  = threadIdx.x;
  const int wave = tid >> 6, lane = tid & 63;
  const int wm = wave >> 2, wn = wave & 3;       // 2M x 4N wave grid
  const int lg = lane >> 4, ll = lane & 15;

  const int nbx = gridDim.x;
  const int id  = blockIdx.y * nbx + blockIdx.x;
  int m_tile, n_tile;
  if (QKV_MAP) {
    const int k = id & 7, q = id >> 3;
    const int ng = q >> 5, r = q & 31;
    m_tile = (k >> 1) * 8 + (r & 7);
    n_tile = (k & 1) * 12 + ng * 4 + (r >> 3);
  } else {
    const int nwg = gridDim.x * gridDim.y;
    const int swz = (id & 7) * (nwg >> 3) + (id >> 3);
    m_tile = swz / nbx;
    n_tile = swz % nbx;
  }
  const int m0 = m_tile * 128, n0 = n_tile * 256;

  f32x4 acc[4][4];
#pragma unroll
  for (int i = 0; i < 4; ++i)
#pragma unroll
    for (int j = 0; j < 4; ++j) acc[i][j] = (f32x4){0.f, 0.f, 0.f, 0.f};

  const unsigned short* aP[2];
  const unsigned short* bP[4];
  int aD[2], bD[4];
#pragma unroll
  for (int i = 0; i < 2; ++i) {
    int cb = (i * 8 + wave) * 64 + lane;
    int cs = cb ^ ((cb >> 3) & 7);
    aP[i] = A + (size_t)(m0 + (cs >> 3)) * K + (cs & 7) * 8;
    aD[i] = cb * 8;
  }
#pragma unroll
  for (int i = 0; i < 4; ++i) {
    int cb = (i * 8 + wave) * 64 + lane;
    int cs = cb ^ ((cb >> 3) & 7);
    bP[i] = Bw + (size_t)(n0 + (cs >> 3)) * K + (cs & 7) * 8;
    bD[i] = cb * 8;
  }

  auto STAGE = [&](int buf, int t) {
    const int kt = t << 6;
#pragma unroll
    for (int i = 0; i < 2; ++i) gload_lds16(aP[i] + kt, &lA[buf][aD[i]]);
#pragma unroll
    for (int i = 0; i < 4; ++i) gload_lds16(bP[i] + kt, &lB[buf][bD[i]]);
  };

  const int xo = (ll & 7) << 4;
  const int laneA0 = wm * 8192 + ((ll * 128 + lg * 16) ^ xo);
  const int laneA1 = wm * 8192 + ((ll * 128 + 64 + lg * 16) ^ xo);
  const int laneB0 = wn * 8192 + ((ll * 128 + lg * 16) ^ xo);
  const int laneB1 = wn * 8192 + ((ll * 128 + 64 + lg * 16) ^ xo);

  const int NT = K >> 6;
  STAGE(0, 0);
  if (NT > 1) {
    STAGE(1, 1);
    asm volatile("s_waitcnt vmcnt(6)" ::: "memory");
  } else {
    asm volatile("s_waitcnt vmcnt(0)" ::: "memory");
  }
  asm volatile("s_barrier" ::: "memory");

  for (int t = 0; t < NT; ++t) {
    const int cur = t % 3;
    const char* pA0 = (const char*)&lA[cur][0] + laneA0;
    const char* pA1 = (const char*)&lA[cur][0] + laneA1;
    const char* pB0 = (const char*)&lB[cur][0] + laneB0;
    const char* pB1 = (const char*)&lB[cur][0] + laneB1;

    bf16x8 af[4][2], bfr[2][2][2];
#pragma unroll
    for (int fq = 0; fq < 4; ++fq) {
      af[fq][0] = load8((const unsigned short*)(pA0 + fq * 2048));
      af[fq][1] = load8((const unsigned short*)(pA1 + fq * 2048));
    }
#pragma unroll
    for (int nh = 0; nh < 2; ++nh)
#pragma unroll
      for (int fq = 0; fq < 2; ++fq) {
        bfr[nh][fq][0] = load8((const unsigned short*)(pB0 + nh * 4096 + fq * 2048));
        bfr[nh][fq][1] = load8((const unsigned short*)(pB1 + nh * 4096 + fq * 2048));
      }

    if (t + 2 < NT) STAGE((t + 2) % 3, t + 2);

    __builtin_amdgcn_s_setprio(1);
#pragma unroll
    for (int nh = 0; nh < 2; ++nh)
#pragma unroll
      for (int fq = 0; fq < 4; ++fq)
#pragma unroll
        for (int gq = 0; gq < 2; ++gq)
#pragma unroll
          for (int kk = 0; kk < 2; ++kk)
            acc[fq][nh * 2 + gq] =
                mfma_bf16(af[fq][kk], bfr[nh][gq][kk], acc[fq][nh * 2 + gq]);
    __builtin_amdgcn_s_setprio(0);

    if (t + 2 < NT)
      asm volatile("s_waitcnt vmcnt(6)" ::: "memory");
    else if (t + 1 < NT)
      asm volatile("s_waitcnt vmcnt(0)" ::: "memory");
    asm volatile("s_barrier" ::: "memory");
  }

#pragma unroll
  for (int fm = 0; fm < 4; ++fm)
#pragma unroll
    for (int fn = 0; fn < 4; ++fn)
#pragma unroll
      for (int j = 0; j < 4; ++j) {
        int r   = m0 + wm * 64 + fm * 16 + lg * 4 + j;
        int col = n0 + wn * 64 + fn * 16 + ll;
        if (OUT_BF16)
          ((unsigned short*)C)[(size_t)r * N + col] = f2bf(acc[fm][fn][j]);
        else
          ((float*)C)[(size_t)r * N + col] = acc[fm][fn][j];
      }
}

// ---------------------------------------------------------------- attention
// 8-wave, KVBLK=128 staging (r22): grid (p=8, bh=32), 512 threads,
// 128 q-rows/block; pairing {p, 15-p} -> 17 kv128-tiles every block.
// Fragment addressing hoisted (r24).
__global__ __launch_bounds__(512, 1)
void attn_kernel(const unsigned short* __restrict__ qr,
                 const unsigned short* __restrict__ kr,
                 const unsigned short* __restrict__ vt,
                 unsigned short* __restrict__ out) {
  __shared__ __align__(16) unsigned short kbuf[2][128 * 128]; // 2 x 32KB
  __shared__ __align__(16) unsigned short vbuf[2][128 * 128]; // 2 x 32KB
  __shared__ __align__(16) unsigned short plds[8][16 * 72];   // 18KB
  const int p = blockIdx.x, bh = blockIdx.y;
  const int wave = threadIdx.x >> 6, lane = threadIdx.x & 63;
  const int b = bh >> 4, h = bh & 15;
  const int lg = lane >> 4, ll = lane & 15;
  const unsigned short* Qb = qr + (size_t)bh * S_DIM * HD_DIM;
  const unsigned short* Kb = kr + (size_t)bh * S_DIM * HD_DIM;
  const unsigned short* Vb = vt + (size_t)bh * HD_DIM * S_DIM;
  const float kE  = 0.12752792f;   // (1/sqrt(128)) * log2(e)
  const float THR = 11.5416f;      // 8 * log2(e)  (T13 threshold, k-domain)
  unsigned short* pw = &plds[wave][0];

  // hoisted per-lane fragment bases (byte offsets)
  const int xo = (ll & 7) << 4;
  int laneK[4], laneV[2];
#pragma unroll
  for (int kk = 0; kk < 4; ++kk)
    laneK[kk] = (ll * 256 + kk * 64 + lg * 16) ^ xo;
#pragma unroll
  for (int c = 0; c < 2; ++c)
    laneV[c] = (ll * 256 + c * 64 + lg * 16) ^ xo;

  for (int seg = 0; seg < 2; ++seg) {
    const int qt = seg ? (15 - p) : p;         // 128-row q-tile index
    const int qbase = qt * 128 + wave * 16;
    const int ntb = qt + 1;                    // kv128-tile count
    const int ntb64 = 2 * qt + 2;              // kv64-half count

    auto STAGE = [&](int buf, int t) {
      const int k0 = t * 128;
#pragma unroll
      for (int i = 0; i < 4; ++i) {
        int cb = (i * 8 + wave) * 64 + lane;   // 0..2047
        int cs = cb ^ ((cb >> 4) & 7);
        gload_lds16(Kb + (size_t)(k0 + (cs >> 4)) * HD_DIM + (cs & 15) * 8,
                    &kbuf[buf][cb * 8]);
      }
#pragma unroll
      for (int i = 0; i < 4; ++i) {
        int cb = (i * 8 + wave) * 64 + lane;
        int cs = cb ^ ((cb >> 4) & 7);
        gload_lds16(Vb + (size_t)(cs >> 4) * S_DIM + k0 + (cs & 15) * 8,
                    &vbuf[buf][cb * 8]);
      }
    };

    bf16x8 aq[4];
#pragma unroll
    for (int kk = 0; kk < 4; ++kk)
      aq[kk] = load8(Qb + (size_t)(qbase + ll) * HD_DIM + kk * 32 + lg * 8);

    float mk[4], lsum[4];
    f32x4 o[8];
#pragma unroll
    for (int j = 0; j < 4; ++j) { mk[j] = -1e30f; lsum[j] = 0.f; }
#pragma unroll
    for (int f = 0; f < 8; ++f) o[f] = (f32x4){0.f, 0.f, 0.f, 0.f};

    STAGE(0, 0);
    __syncthreads();   // implicit vmcnt(0) drain

    for (int t = 0; t < ntb; ++t) {
      const int cur = t & 1;
      if (t + 1 < ntb) STAGE(cur ^ 1, t + 1);  // full-tile latency cover
      const char* kb = (const char*)&kbuf[cur][0];
      const char* vb = (const char*)&vbuf[cur][0];

#pragma unroll
      for (int half = 0; half < 2; ++half) {
        const int th = 2 * t + half;           // kv64-half index
        const int k0h = th * 64;
        const bool maskt = (th >= ntb64 - 2);  // block-uniform

        f32x4 s[4];
#pragma unroll
        for (int kf = 0; kf < 4; ++kf) s[kf] = (f32x4){0.f, 0.f, 0.f, 0.f};
        __builtin_amdgcn_s_setprio(1);
#pragma unroll
        for (int kf = 0; kf < 4; ++kf)
#pragma unroll
          for (int kk = 0; kk < 4; ++kk)
            s[kf] = mfma_bf16(
                aq[kk],
                load8((const unsigned short*)(kb + laneK[kk] + half * 16384 +
                                              kf * 4096)),
                s[kf]);
        __builtin_amdgcn_s_setprio(0);

        if (maskt) {
#pragma unroll
          for (int kf = 0; kf < 4; ++kf) {
            int kcol = k0h + kf * 16 + ll;
#pragma unroll
            for (int j = 0; j < 4; ++j) {
              int qrow = qbase + lg * 4 + j;
              if (kcol > qrow) s[kf][j] = -1e31f;
            }
          }
        }

        float pmax[4];
        bool ok = true;
#pragma unroll
        for (int j = 0; j < 4; ++j) {
          pmax[j] = fmaxf(fmaxf(s[0][j], s[1][j]), fmaxf(s[2][j], s[3][j]));
          ok = ok && (pmax[j] * kE - mk[j] <= THR);
        }
        if (!__all(ok)) {                      // rare: ~once per segment
#pragma unroll
          for (int j = 0; j < 4; ++j) {
            float rm = pmax[j] * kE;
#pragma unroll
            for (int off = 1; off < 16; off <<= 1)
              rm = fmaxf(rm, __shfl_xor(rm, off, 64));
            rm = fmaxf(rm, mk[j]);
            float corr = exp2f(mk[j] - rm);
            mk[j] = rm;
            lsum[j] *= corr;
#pragma unroll
            for (int f = 0; f < 8; ++f) o[f][j] *= corr;
          }
        }
#pragma unroll
        for (int j = 0; j < 4; ++j) {
          int prow = (lg * 4 + j) * 72;
#pragma unroll
          for (int kf = 0; kf < 4; ++kf) {
            float e = exp2f(fmaf(s[kf][j], kE, -mk[j]));
            lsum[j] += e;
            pw[prow + kf * 16 + ll] = f2bf(e);
          }
        }

        bf16x8 pa0 = load8(&pw[ll * 72 + lg * 8]);
        bf16x8 pa1 = load8(&pw[ll * 72 + 32 + lg * 8]);
        __builtin_amdgcn_s_setprio(1);
#pragma unroll
        for (int f = 0; f < 8; ++f) {
          o[f] = mfma_bf16(
              pa0,
              load8((const unsigned short*)(vb + laneV[0] + f * 4096 +
                                            half * 128)),
              o[f]);
          o[f] = mfma_bf16(
              pa1,
              load8((const unsigned short*)(vb + laneV[1] + f * 4096 +
                                            half * 128)),
              o[f]);
        }
        __builtin_amdgcn_s_setprio(0);
      }

      __syncthreads();   // once per 128-tile: drains staged vmcnt + dbuf guard
    }

#pragma unroll
    for (int j = 0; j < 4; ++j) {
      float l = lsum[j];
#pragma unroll
      for (int off = 1; off < 16; off <<= 1) l += __shfl_xor(l, off, 64);
      lsum[j] = 1.0f / l;
    }
#pragma unroll
    for (int f = 0; f < 8; ++f)
#pragma unroll
      for (int j = 0; j < 4; ++j) {
        int srow = qbase + lg * 4 + j;
        out[((size_t)(b * S_DIM + srow)) * H_DIM + h * HD_DIM + f * 16 + ll] =
            f2bf(o[f][j] * lsum[j]);
      }
  }
}

// ---------------------------------------------------------------- launch
extern "C" void kernel_launch(void* const* d_in, const int* in_sizes, int n_in,
                              void* d_out, int out_size, void* d_ws, size_t ws_size,
                              hipStream_t stream) {
  (void)in_sizes; (void)n_in; (void)out_size; (void)ws_size;
  const float* hidden = (const float*)d_in[0];
  const float* wqkv   = (const float*)d_in[1];
  const float* wo     = (const float*)d_in[2];
  char* ws = (char*)d_ws;
  unsigned short* hid_b  = (unsigned short*)(ws);               // 16,777,216
  unsigned short* wqkv_b = (unsigned short*)(ws + 16777216);    // 25,165,824
  unsigned short* wo_b   = (unsigned short*)(ws + 41943040);    //  8,388,608
  unsigned short* q_r    = (unsigned short*)(ws + 100663296);   // 16,777,216
  unsigned short* k_r    = (unsigned short*)(ws + 117440512);   // 16,777,216
  unsigned short* v_t    = (unsigned short*)(ws + 134217728);   // 16,777,216
  unsigned short* attn   = (unsigned short*)(ws + 150994944);   // 16,777,216
  float* cosT            = (float*)(ws + 167772160);            //    524,288
  float* sinT            = (float*)(ws + 168296448);            //    524,288

  prep_kernel<<<2048, 256, 0, stream>>>(hidden, wqkv, wo, hid_b, wqkv_b, wo_b,
                                        cosT, sinT);

  // QKV projection + fused RoPE + fused V-transpose: grid 24x32 = 3 rounds
  gemm_qkv_kernel<<<dim3(O3 / 256, BS / 128), 512, 0, stream>>>(
      hid_b, wqkv_b, q_r, k_r, v_t, cosT, sinT, BS, O3, H_DIM);

  // attention: 8-wave blocks, KVBLK=128 staging, grid 8x32 = 256 = 1/CU
  attn_kernel<<<dim3(8, 32), 512, 0, stream>>>(q_r, k_r, v_t, attn);

  // output projection: grid 8x32 = 256 = exactly 1 round; chunked map
  gemm3b_kernel<false, false><<<dim3(H_DIM / 256, BS / 128), 512, 0, stream>>>(
      attn, wo_b, d_out, BS, H_DIM, H_DIM);
}